// Round 1
// baseline (1536.484 us; speedup 1.0000x reference)
//
#include <hip/hip_runtime.h>
#include <stdint.h>

#define NIMG 4
#define PTOT 8400
#define NCLS 80
#define NW   132            // 64-bit words per mask row (ceil(8400/64))
#define SPAN 16             // rows per scan staging span
#define NSPAN (PTOT / SPAN) // 525
#define NMS_THR_C 0.65f
#define SCORE_THR_C 0.01f

static __device__ __forceinline__ float sigmoidf_(float x) {
  return 1.0f / (1.0f + expf(-x));
}
// order-preserving float->uint encoding for atomicMax
static __device__ __forceinline__ unsigned enc_f(float f) {
  unsigned u = __float_as_uint(f);
  return (u >> 31) ? ~u : (u | 0x80000000u);
}
static __device__ __forceinline__ float dec_f(unsigned e) {
  return (e >> 31) ? __uint_as_float(e ^ 0x80000000u) : __uint_as_float(~e);
}

__global__ void k_init(unsigned* gmax) {
  int t = threadIdx.x;
  if (t < NIMG) gmax[t] = 0u;  // below every encoded float
}

// ---------------- decode: sigmoid + argmax + box decode + per-image coord max
__global__ __launch_bounds__(64) void k_decode(
    const float* __restrict__ cls0, const float* __restrict__ cls1, const float* __restrict__ cls2,
    const float* __restrict__ reg0, const float* __restrict__ reg1, const float* __restrict__ reg2,
    const float* __restrict__ obj0, const float* __restrict__ obj1, const float* __restrict__ obj2,
    float* __restrict__ score, int* __restrict__ label, float* __restrict__ boxes,
    unsigned* __restrict__ gmax)
{
  int t = blockIdx.x * 64 + threadIdx.x;   // grid = 525*64 == 33600 exactly
  int n = t / PTOT;
  int p = t - n * PTOT;
  const float* cb; const float* rb; const float* ob;
  int HW, W, pl; float s;
  if (p < 6400)      { cb = cls0; rb = reg0; ob = obj0; HW = 6400; W = 80; pl = p;        s = 8.f;  }
  else if (p < 8000) { cb = cls1; rb = reg1; ob = obj1; HW = 1600; W = 40; pl = p - 6400; s = 16.f; }
  else               { cb = cls2; rb = reg2; ob = obj2; HW = 400;  W = 20; pl = p - 8000; s = 32.f; }

  // argmax over sigmoid(cls) — first max wins (replicates jnp.argmax on sigmoid values)
  const float* cp = cb + (size_t)n * NCLS * HW + pl;
  float best = -1.0f; int bi = 0;
  for (int c = 0; c < NCLS; ++c) {
    float v = sigmoidf_(cp[(size_t)c * HW]);
    if (v > best) { best = v; bi = c; }
  }
  float osg = sigmoidf_(ob[(size_t)n * HW + pl]);
  float sc = best * osg;

  const float* rp = rb + (size_t)n * 4 * HW + pl;
  float rx = rp[0], ry = rp[(size_t)HW], rw = rp[(size_t)2 * HW], rh = rp[(size_t)3 * HW];
  int ph = pl / W, pw = pl - ph * W;
  float px = (float)pw * s, py = (float)ph * s;
  float cx = rx * s + px, cy = ry * s + py;
  float bw = expf(rw) * s, bh = expf(rh) * s;
  float x1 = cx - bw * 0.5f, y1 = cy - bh * 0.5f;
  float x2 = cx + bw * 0.5f, y2 = cy + bh * 0.5f;

  score[t] = sc;
  label[t] = bi;
  float* bx = boxes + (size_t)t * 4;
  bx[0] = x1; bx[1] = y1; bx[2] = x2; bx[3] = y2;

  // per-image max over all box coords (for the class-offset trick)
  float m = fmaxf(fmaxf(x1, y1), fmaxf(x2, y2));
  unsigned long long samen = __ballot(n == __shfl(n, 0, 64));
  if (samen == ~0ull) {
    for (int o = 32; o; o >>= 1) m = fmaxf(m, __shfl_xor(m, o, 64));
    if (threadIdx.x == 0) atomicMax(&gmax[n], enc_f(m));
  } else {
    atomicMax(&gmax[n], enc_f(m));  // rare boundary waves
  }
}

// ---------------- stable descending rank sort + build shifted boxes/areas
__global__ __launch_bounds__(256) void k_rank(
    const float* __restrict__ score, const int* __restrict__ label, const float* __restrict__ boxes,
    const unsigned* __restrict__ gmax,
    float* __restrict__ s_score, int* __restrict__ s_label,
    float* __restrict__ s_box, float* __restrict__ s_sbox, float* __restrict__ s_area)
{
  __shared__ float keys[PTOT];   // 33.6 KB
  int n = blockIdx.y;
  int tid = threadIdx.x;
  const float* sc = score + (size_t)n * PTOT;
  for (int j = tid; j < PTOT; j += 256) {
    float v = sc[j];
    keys[j] = (v >= SCORE_THR_C) ? v : -1.0f;
  }
  __syncthreads();
  int i = blockIdx.x * 256 + tid;
  if (i >= PTOT) return;
  float ki = keys[i];
  int cnt = 0;
#pragma unroll 8
  for (int j = 0; j < PTOT; ++j) {
    float kj = keys[j];
    cnt += (int)(kj > ki) + (int)((kj == ki) && (j < i));
  }
  int r = cnt;  // rank is a permutation (total order)

  float gm = dec_f(gmax[n]);
  int li = label[(size_t)n * PTOT + i];
  const float* bp = boxes + ((size_t)n * PTOT + i) * 4;
  float b0 = bp[0], b1 = bp[1], b2 = bp[2], b3 = bp[3];
  float off = (float)li * (gm + 1.0f);
  float q0 = b0 + off, q1 = b1 + off, q2 = b2 + off, q3 = b3 + off;
  float area = (q2 - q0) * (q3 - q1);   // area from SHIFTED coords (matches reference)

  size_t d = (size_t)n * PTOT + (size_t)r;
  s_score[d] = sc[i];
  s_label[d] = li;
  float* sb = s_box + d * 4;  sb[0] = b0; sb[1] = b1; sb[2] = b2; sb[3] = b3;
  float* sq = s_sbox + d * 4; sq[0] = q0; sq[1] = q1; sq[2] = q2; sq[3] = q3;
  s_area[d] = area;
}

// ---------------- pairwise IoU suppression bitmask (upper triangle, 64x64 tiles)
__global__ __launch_bounds__(64) void k_mask(
    const float* __restrict__ s_sbox, const float* __restrict__ s_area,
    uint64_t* __restrict__ mask)
{
  int c = blockIdx.x, r = blockIdx.y, n = blockIdx.z;
  if (c < r) return;  // whole block uniform exit (no barrier executed)
  int l = threadIdx.x;
  __shared__ float cbx[64], cby[64], cbX[64], cbY[64], cba[64];
  int j = c * 64 + l;
  if (j < PTOT) {
    const float* q = s_sbox + ((size_t)n * PTOT + j) * 4;
    cbx[l] = q[0]; cby[l] = q[1]; cbX[l] = q[2]; cbY[l] = q[3];
    cba[l] = s_area[(size_t)n * PTOT + j];
  } else {
    cbx[l] = 0.f; cby[l] = 0.f; cbX[l] = 0.f; cbY[l] = 0.f; cba[l] = 0.f;
  }
  __syncthreads();
  int i = r * 64 + l;
  float ax1 = 0.f, ay1 = 0.f, ax2 = 0.f, ay2 = 0.f, aa = 0.f;
  if (i < PTOT) {
    const float* q = s_sbox + ((size_t)n * PTOT + i) * 4;
    ax1 = q[0]; ay1 = q[1]; ax2 = q[2]; ay2 = q[3];
    aa = s_area[(size_t)n * PTOT + i];
  }
  uint64_t w = 0;
#pragma unroll 4
  for (int jj = 0; jj < 64; ++jj) {
    float ltx = fmaxf(ax1, cbx[jj]);
    float lty = fmaxf(ay1, cby[jj]);
    float rbx = fminf(ax2, cbX[jj]);
    float rby = fminf(ay2, cbY[jj]);
    float ww = fmaxf(rbx - ltx, 0.0f);
    float hh = fmaxf(rby - lty, 0.0f);
    float inter = ww * hh;
    float uni = fmaxf(aa + cba[jj] - inter, 1e-12f);
    float iou = inter / uni;           // real division to match reference rounding
    int jg = c * 64 + jj;
    bool bit = (iou > NMS_THR_C) && (jg > i) && (jg < PTOT);
    w |= ((uint64_t)bit) << jj;
  }
  if (i < PTOT) mask[((size_t)n * PTOT + (size_t)i) * NW + c] = w;
}

// ---------------- greedy suppression scan: 1 wave per image
__global__ __launch_bounds__(64) void k_scan(
    const uint64_t* __restrict__ mask,
    const float* __restrict__ s_score, uint64_t* __restrict__ keepw)
{
  __shared__ uint64_t buf[2][SPAN * NW];  // 2 * 16.9 KB
  int n = blockIdx.x, l = threadIdx.x;

  // removed-bitmask in registers: lane l owns words l, 64+l, (l<4: 128+l)
  uint64_t r0 = 0, r1 = 0, r2 = 0;
  const float* sc = s_score + (size_t)n * PTOT;
  for (int w = 0; w < NW; ++w) {
    int j = w * 64 + l;
    bool invalid = true;
    if (j < PTOT) invalid = !(sc[j] >= SCORE_THR_C);
    uint64_t m = __ballot(invalid);
    if (w == l) r0 = m;
    else if (w == 64 + l) r1 = m;
    else if (w == 128 + l) r2 = m;
  }

  const uint64_t* mrow = mask + (size_t)n * PTOT * NW;

  // prologue: span 0 straight to LDS, span 1 into regs
  for (int k = l; k < SPAN * NW; k += 64) buf[0][k] = mrow[k];
  uint64_t pre[33];
  {
    const uint64_t* g = mrow + (size_t)1 * SPAN * NW;
#pragma unroll
    for (int q = 0; q < 33; ++q) pre[q] = g[q * 64 + l];
  }

  for (int s = 0; s < NSPAN; ++s) {
    __syncthreads();  // publish last iteration's (and prologue's) LDS writes
    if (s + 1 < NSPAN) {
      uint64_t* dst = &buf[(s + 1) & 1][0];
#pragma unroll
      for (int q = 0; q < 33; ++q) dst[q * 64 + l] = pre[q];
    }
    if (s + 2 < NSPAN) {
      const uint64_t* g = mrow + (size_t)(s + 2) * SPAN * NW;
#pragma unroll
      for (int q = 0; q < 33; ++q) pre[q] = g[q * 64 + l];
    }
    const uint64_t* Bp = &buf[s & 1][0];
    // depth-2 register prefetch of row words
    uint64_t pa0 = Bp[0 * NW + l], pa1 = Bp[0 * NW + 64 + l], pa2 = Bp[0 * NW + 128 + (l & 3)];
    uint64_t pb0 = Bp[1 * NW + l], pb1 = Bp[1 * NW + 64 + l], pb2 = Bp[1 * NW + 128 + (l & 3)];
#pragma unroll
    for (int k = 0; k < SPAN; ++k) {
      uint64_t a0 = pa0, a1 = pa1, a2 = pa2;
      pa0 = pb0; pa1 = pb1; pa2 = pb2;
      if (k + 2 < SPAN) {
        pb0 = Bp[(k + 2) * NW + l];
        pb1 = Bp[(k + 2) * NW + 64 + l];
        pb2 = Bp[(k + 2) * NW + 128 + (l & 3)];
      }
      int i = s * SPAN + k;
      int wi = i >> 6, b = i & 63;
      uint64_t srcw = (wi < 64) ? r0 : ((wi < 128) ? r1 : r2);
      uint64_t cur = __shfl(srcw, wi & 63, 64);   // uniform broadcast
      if (!((cur >> b) & 1ull)) {
        // OR row i, but only bits j>i (words < wi hold unwritten garbage)
        uint64_t part = (~1ull) << b;             // bits strictly greater than b (b==63 -> 0)
        int w0 = l, w1 = 64 + l, w2 = 128 + (l & 3);
        uint64_t m0 = (w0 > wi) ? ~0ull : ((w0 == wi) ? part : 0ull);
        uint64_t m1 = (w1 > wi) ? ~0ull : ((w1 == wi) ? part : 0ull);
        uint64_t m2 = (w2 > wi) ? ~0ull : ((w2 == wi) ? part : 0ull);
        r0 |= a0 & m0; r1 |= a1 & m1; r2 |= a2 & m2;
      }
    }
  }

  keepw[(size_t)n * NW + l] = ~r0;
  keepw[(size_t)n * NW + 64 + l] = ~r1;
  if (l < 4) keepw[(size_t)n * NW + 128 + l] = ~r2;
}

// ---------------- finalize outputs
__global__ __launch_bounds__(256) void k_final(
    const float* __restrict__ s_score, const int* __restrict__ s_label,
    const float* __restrict__ s_box, const uint64_t* __restrict__ keepw,
    float* __restrict__ out)
{
  int t = blockIdx.x * 256 + threadIdx.x;
  if (t >= NIMG * PTOT) return;
  int n = t / PTOT, p = t - n * PTOT;
  uint64_t w = keepw[(size_t)n * NW + (p >> 6)];
  float k = (float)((w >> (p & 63)) & 1ull);
  float* dets = out;
  float* lab  = out + (size_t)NIMG * PTOT * 5;
  float* kp   = out + (size_t)NIMG * PTOT * 6;
  const float* bp = s_box + (size_t)t * 4;
  float* dp = dets + (size_t)t * 5;
  dp[0] = bp[0] * k; dp[1] = bp[1] * k; dp[2] = bp[2] * k; dp[3] = bp[3] * k;
  dp[4] = s_score[t] * k;
  lab[t] = (float)s_label[t];
  kp[t]  = k;
}

extern "C" void kernel_launch(void* const* d_in, const int* in_sizes, int n_in,
                              void* d_out, int out_size, void* d_ws, size_t ws_size,
                              hipStream_t stream)
{
  const float* cls0 = (const float*)d_in[0];
  const float* cls1 = (const float*)d_in[1];
  const float* cls2 = (const float*)d_in[2];
  const float* reg0 = (const float*)d_in[3];
  const float* reg1 = (const float*)d_in[4];
  const float* reg2 = (const float*)d_in[5];
  const float* obj0 = (const float*)d_in[6];
  const float* obj1 = (const float*)d_in[7];
  const float* obj2 = (const float*)d_in[8];

  char* w = (char*)d_ws;
  uint64_t* mask = (uint64_t*)w;  w += (size_t)NIMG * PTOT * NW * 8;  // 35,481,600 B
  uint64_t* keepw = (uint64_t*)w; w += (size_t)NIMG * NW * 8;
  float* score = (float*)w;       w += (size_t)NIMG * PTOT * 4;
  int*   label = (int*)w;         w += (size_t)NIMG * PTOT * 4;
  float* boxes = (float*)w;       w += (size_t)NIMG * PTOT * 16;
  float* ss = (float*)w;          w += (size_t)NIMG * PTOT * 4;
  int*   sl = (int*)w;            w += (size_t)NIMG * PTOT * 4;
  float* sb = (float*)w;          w += (size_t)NIMG * PTOT * 16;
  float* sq = (float*)w;          w += (size_t)NIMG * PTOT * 16;
  float* sa = (float*)w;          w += (size_t)NIMG * PTOT * 4;
  unsigned* gmax = (unsigned*)w;  w += (size_t)NIMG * 4;

  k_init<<<dim3(1), dim3(64), 0, stream>>>(gmax);
  k_decode<<<dim3((NIMG * PTOT) / 64), dim3(64), 0, stream>>>(
      cls0, cls1, cls2, reg0, reg1, reg2, obj0, obj1, obj2,
      score, label, boxes, gmax);
  k_rank<<<dim3((PTOT + 255) / 256, NIMG), dim3(256), 0, stream>>>(
      score, label, boxes, gmax, ss, sl, sb, sq, sa);
  k_mask<<<dim3(NW, NW, NIMG), dim3(64), 0, stream>>>(sq, sa, mask);
  k_scan<<<dim3(NIMG), dim3(64), 0, stream>>>(mask, ss, keepw);
  k_final<<<dim3((NIMG * PTOT + 255) / 256), dim3(256), 0, stream>>>(
      ss, sl, sb, keepw, (float*)d_out);
}

// Round 2
// 439.516 us; speedup vs baseline: 3.4959x; 3.4959x over previous
//
#include <hip/hip_runtime.h>
#include <stdint.h>

#define NIMG 4
#define PTOT 8400
#define NCLS 80
#define NW   132            // 64-bit words per mask row (ceil(8400/64))
#define DSTR (NW * 64)      // 8448: padded rows per image in diag array
#define NMS_THR_C 0.65f
#define SCORE_THR_C 0.01f

static __device__ __forceinline__ float sigmoidf_(float x) {
  return 1.0f / (1.0f + expf(-x));
}
// order-preserving float->uint encoding for atomicMax
static __device__ __forceinline__ unsigned enc_f(float f) {
  unsigned u = __float_as_uint(f);
  return (u >> 31) ? ~u : (u | 0x80000000u);
}
static __device__ __forceinline__ float dec_f(unsigned e) {
  return (e >> 31) ? __uint_as_float(e ^ 0x80000000u) : __uint_as_float(~e);
}

__global__ void k_init(unsigned* gmax, uint64_t* flags, int* nvalid, uint64_t* diag) {
  int t = threadIdx.x;  // one block of 256
  if (t < NIMG) { gmax[t] = 0u; nvalid[t] = 0; }
  for (int k = t; k < NIMG * NW; k += 256) flags[k] = 0ull;
  // zero the diag tail rows (8400..8447) so chunk 131 reads are clean
  if (t < NIMG * (DSTR - PTOT)) {
    int nn = t / (DSTR - PTOT), kk = t - nn * (DSTR - PTOT);
    diag[(size_t)nn * DSTR + PTOT + kk] = 0ull;
  }
}

// ---------------- decode: sigmoid + argmax + box decode + per-image coord max
__global__ __launch_bounds__(64) void k_decode(
    const float* __restrict__ cls0, const float* __restrict__ cls1, const float* __restrict__ cls2,
    const float* __restrict__ reg0, const float* __restrict__ reg1, const float* __restrict__ reg2,
    const float* __restrict__ obj0, const float* __restrict__ obj1, const float* __restrict__ obj2,
    float* __restrict__ score, int* __restrict__ label, float* __restrict__ boxes,
    unsigned* __restrict__ gmax)
{
  int t = blockIdx.x * 64 + threadIdx.x;   // grid = 525*64 == 33600 exactly
  int n = t / PTOT;
  int p = t - n * PTOT;
  const float* cb; const float* rb; const float* ob;
  int HW, W, pl; float s;
  if (p < 6400)      { cb = cls0; rb = reg0; ob = obj0; HW = 6400; W = 80; pl = p;        s = 8.f;  }
  else if (p < 8000) { cb = cls1; rb = reg1; ob = obj1; HW = 1600; W = 40; pl = p - 6400; s = 16.f; }
  else               { cb = cls2; rb = reg2; ob = obj2; HW = 400;  W = 20; pl = p - 8000; s = 32.f; }

  // argmax over sigmoid(cls) — first max wins (replicates jnp.argmax on sigmoid values)
  const float* cp = cb + (size_t)n * NCLS * HW + pl;
  float best = -1.0f; int bi = 0;
  for (int c = 0; c < NCLS; ++c) {
    float v = sigmoidf_(cp[(size_t)c * HW]);
    if (v > best) { best = v; bi = c; }
  }
  float osg = sigmoidf_(ob[(size_t)n * HW + pl]);
  float sc = best * osg;

  const float* rp = rb + (size_t)n * 4 * HW + pl;
  float rx = rp[0], ry = rp[(size_t)HW], rw = rp[(size_t)2 * HW], rh = rp[(size_t)3 * HW];
  int ph = pl / W, pw = pl - ph * W;
  float px = (float)pw * s, py = (float)ph * s;
  float cx = rx * s + px, cy = ry * s + py;
  float bw = expf(rw) * s, bh = expf(rh) * s;
  float x1 = cx - bw * 0.5f, y1 = cy - bh * 0.5f;
  float x2 = cx + bw * 0.5f, y2 = cy + bh * 0.5f;

  score[t] = sc;
  label[t] = bi;
  float* bx = boxes + (size_t)t * 4;
  bx[0] = x1; bx[1] = y1; bx[2] = x2; bx[3] = y2;

  // per-image max over all box coords (for the class-offset trick)
  float m = fmaxf(fmaxf(x1, y1), fmaxf(x2, y2));
  unsigned long long samen = __ballot(n == __shfl(n, 0, 64));
  if (samen == ~0ull) {
    for (int o = 32; o; o >>= 1) m = fmaxf(m, __shfl_xor(m, o, 64));
    if (threadIdx.x == 0) atomicMax(&gmax[n], enc_f(m));
  } else {
    atomicMax(&gmax[n], enc_f(m));  // rare boundary waves
  }
}

// ---------------- stable descending rank sort + build shifted boxes/areas
__global__ __launch_bounds__(256) void k_rank(
    const float* __restrict__ score, const int* __restrict__ label, const float* __restrict__ boxes,
    const unsigned* __restrict__ gmax, int* __restrict__ nvalid,
    float* __restrict__ s_score, int* __restrict__ s_label,
    float* __restrict__ s_box, float* __restrict__ s_sbox, float* __restrict__ s_area)
{
  __shared__ float keys[PTOT];   // 33.6 KB
  int n = blockIdx.y;
  int tid = threadIdx.x;
  const float* sc = score + (size_t)n * PTOT;
  for (int j = tid; j < PTOT; j += 256) {
    float v = sc[j];
    keys[j] = (v >= SCORE_THR_C) ? v : -1.0f;
  }
  __syncthreads();
  int i = blockIdx.x * 256 + tid;
  if (i >= PTOT) return;
  float ki = keys[i];
  int cnt = 0;
#pragma unroll 8
  for (int j = 0; j < PTOT; ++j) {
    float kj = keys[j];
    cnt += (int)(kj > ki) + (int)((kj == ki) && (j < i));
  }
  int r = cnt;  // rank is a permutation (total order)

  // count valid boxes (sorted order puts all valid first -> removed-init is a suffix)
  bool valid = (ki != -1.0f);
  unsigned long long bal = __ballot(valid);
  if ((tid & 63) == 0) atomicAdd(&nvalid[n], (int)__popcll(bal));

  float gm = dec_f(gmax[n]);
  int li = label[(size_t)n * PTOT + i];
  const float* bp = boxes + ((size_t)n * PTOT + i) * 4;
  float b0 = bp[0], b1 = bp[1], b2 = bp[2], b3 = bp[3];
  float off = (float)li * (gm + 1.0f);
  float q0 = b0 + off, q1 = b1 + off, q2 = b2 + off, q3 = b3 + off;
  float area = (q2 - q0) * (q3 - q1);   // area from SHIFTED coords (matches reference)

  size_t d = (size_t)n * PTOT + (size_t)r;
  s_score[d] = sc[i];
  s_label[d] = li;
  float* sb = s_box + d * 4;  sb[0] = b0; sb[1] = b1; sb[2] = b2; sb[3] = b3;
  float* sq = s_sbox + d * 4; sq[0] = q0; sq[1] = q1; sq[2] = q2; sq[3] = q3;
  s_area[d] = area;
}

// ---------------- pairwise IoU suppression bitmask (upper triangle, 64x64 tiles)
// c == r: write compact diag word. c > r: write mask row word + row-nonzero flag.
__global__ __launch_bounds__(64) void k_mask(
    const float* __restrict__ s_sbox, const float* __restrict__ s_area,
    uint64_t* __restrict__ mask, uint64_t* __restrict__ diag, uint64_t* __restrict__ flags)
{
  int c = blockIdx.x, r = blockIdx.y, n = blockIdx.z;
  if (c < r) return;  // whole block uniform exit (no barrier executed)
  int l = threadIdx.x;
  __shared__ float cbx[64], cby[64], cbX[64], cbY[64], cba[64];
  int j = c * 64 + l;
  if (j < PTOT) {
    const float* q = s_sbox + ((size_t)n * PTOT + j) * 4;
    cbx[l] = q[0]; cby[l] = q[1]; cbX[l] = q[2]; cbY[l] = q[3];
    cba[l] = s_area[(size_t)n * PTOT + j];
  } else {
    cbx[l] = 0.f; cby[l] = 0.f; cbX[l] = 0.f; cbY[l] = 0.f; cba[l] = 0.f;
  }
  __syncthreads();
  int i = r * 64 + l;
  float ax1 = 0.f, ay1 = 0.f, ax2 = 0.f, ay2 = 0.f, aa = 0.f;
  if (i < PTOT) {
    const float* q = s_sbox + ((size_t)n * PTOT + i) * 4;
    ax1 = q[0]; ay1 = q[1]; ax2 = q[2]; ay2 = q[3];
    aa = s_area[(size_t)n * PTOT + i];
  }
  uint64_t w = 0;
#pragma unroll 4
  for (int jj = 0; jj < 64; ++jj) {
    float ltx = fmaxf(ax1, cbx[jj]);
    float lty = fmaxf(ay1, cby[jj]);
    float rbx = fminf(ax2, cbX[jj]);
    float rby = fminf(ay2, cbY[jj]);
    float ww = fmaxf(rbx - ltx, 0.0f);
    float hh = fmaxf(rby - lty, 0.0f);
    float inter = ww * hh;
    float uni = fmaxf(aa + cba[jj] - inter, 1e-12f);
    float iou = inter / uni;           // real division to match reference rounding
    int jg = c * 64 + jj;
    bool bit = (iou > NMS_THR_C) && (jg > i) && (jg < PTOT);
    w |= ((uint64_t)bit) << jj;
  }
  bool realrow = (i < PTOT);
  if (c == r) {
    if (realrow) diag[(size_t)n * DSTR + i] = w;
  } else {
    if (realrow) mask[((size_t)n * PTOT + (size_t)i) * NW + c] = w;
    unsigned long long bal = __ballot(realrow && (w != 0ull));
    if (l == 0 && bal) atomicOr((unsigned long long*)&flags[(size_t)n * NW + r], bal);
  }
}

// ---------------- greedy suppression scan: 1 wave per image, sparse chunk walk
__global__ __launch_bounds__(64) void k_scan(
    const uint64_t* __restrict__ mask,
    const uint64_t* __restrict__ diag,
    const uint64_t* __restrict__ flags,
    const int* __restrict__ nvalid,
    uint64_t* __restrict__ keepw)
{
  int n = blockIdx.x, l = threadIdx.x;
  int nv = nvalid[n];

  // removed-mask init: sorted order puts invalid boxes last -> removed = bits >= nv
  // lane l owns words l, 64+l, (l<4: 128+l)
  auto initw = [&](int w) -> uint64_t {
    int base = w * 64;
    if (nv <= base) return ~0ull;
    if (nv >= base + 64) return 0ull;
    return (~0ull) << (nv - base);
  };
  uint64_t r0 = initw(l), r1 = initw(64 + l), r2 = (l < 4) ? initw(128 + l) : 0ull;

  const uint64_t* fl = flags + (size_t)n * NW;
  uint64_t f0 = fl[l], f1 = fl[64 + l], f2 = (l < 4) ? fl[128 + l] : 0ull;
  const uint64_t* dg = diag + (size_t)n * DSTR;
  const uint64_t* mrow = mask + (size_t)n * PTOT * NW;

  // diag word prefetch, depth 2 (lane l holds row c*64+l's in-chunk word)
  uint64_t dcur = dg[l];
  uint64_t dnxt = dg[64 + l];

  for (int c = 0; c < NW; ++c) {
    uint64_t d = dcur;
    dcur = dnxt;
    if (c + 2 < NW) dnxt = dg[(size_t)(c + 2) * 64 + l];

    int ol = c & 63;  // owner lane of word c in its slot
    uint64_t srcw = (c < 64) ? r0 : ((c < 128) ? r1 : r2);
    uint64_t R = __shfl(srcw, ol, 64);          // removed word for this chunk (uniform)
    uint64_t fsrc = (c < 64) ? f0 : ((c < 128) ? f1 : f2);
    uint64_t F = __shfl(fsrc, ol, 64);          // rows with off-diag suppression bits

    // in-chunk greedy resolve: only rows with nonzero diag words matter
    uint64_t nz = __ballot(d != 0ull);
    uint64_t pending = nz & ~R;
    while (pending) {
      int b = __builtin_ctzll(pending);
      uint64_t row = __shfl(d, b, 64);          // bits only for j>b within chunk
      R |= row;
      pending &= ~R;
      pending &= pending - 1;                    // clear bit b (still lowest)
    }
    if (l == ol) { if (c < 64) r0 = R; else if (c < 128) r1 = R; else r2 = R; }

    // OR full rows of kept+flagged boxes into future removed words (word > c only)
    uint64_t kf = F & ~R;
    uint64_t m0 = (l > c) ? ~0ull : 0ull;
    uint64_t m1 = (64 + l > c) ? ~0ull : 0ull;
    uint64_t m2 = (128 + l > c) ? ~0ull : 0ull;
    while (kf) {
      int b1 = __builtin_ctzll(kf); kf &= kf - 1;
      const uint64_t* rp1 = mrow + (size_t)(c * 64 + b1) * NW;
      uint64_t a0 = rp1[l], a1 = rp1[64 + l], a2 = (l < 4) ? rp1[128 + l] : 0ull;
      if (kf) {  // 2-way unroll to overlap load latency
        int b2 = __builtin_ctzll(kf); kf &= kf - 1;
        const uint64_t* rp2 = mrow + (size_t)(c * 64 + b2) * NW;
        uint64_t c0 = rp2[l], c1 = rp2[64 + l], c2 = (l < 4) ? rp2[128 + l] : 0ull;
        a0 |= c0; a1 |= c1; a2 |= c2;
      }
      r0 |= a0 & m0;
      r1 |= a1 & m1;
      if (l < 4) r2 |= a2 & m2;
    }
  }

  keepw[(size_t)n * NW + l] = ~r0;
  keepw[(size_t)n * NW + 64 + l] = ~r1;
  if (l < 4) keepw[(size_t)n * NW + 128 + l] = ~r2;
}

// ---------------- finalize outputs
__global__ __launch_bounds__(256) void k_final(
    const float* __restrict__ s_score, const int* __restrict__ s_label,
    const float* __restrict__ s_box, const uint64_t* __restrict__ keepw,
    float* __restrict__ out)
{
  int t = blockIdx.x * 256 + threadIdx.x;
  if (t >= NIMG * PTOT) return;
  int n = t / PTOT, p = t - n * PTOT;
  uint64_t w = keepw[(size_t)n * NW + (p >> 6)];
  float k = (float)((w >> (p & 63)) & 1ull);
  float* dets = out;
  float* lab  = out + (size_t)NIMG * PTOT * 5;
  float* kp   = out + (size_t)NIMG * PTOT * 6;
  const float* bp = s_box + (size_t)t * 4;
  float* dp = dets + (size_t)t * 5;
  dp[0] = bp[0] * k; dp[1] = bp[1] * k; dp[2] = bp[2] * k; dp[3] = bp[3] * k;
  dp[4] = s_score[t] * k;
  lab[t] = (float)s_label[t];
  kp[t]  = k;
}

extern "C" void kernel_launch(void* const* d_in, const int* in_sizes, int n_in,
                              void* d_out, int out_size, void* d_ws, size_t ws_size,
                              hipStream_t stream)
{
  const float* cls0 = (const float*)d_in[0];
  const float* cls1 = (const float*)d_in[1];
  const float* cls2 = (const float*)d_in[2];
  const float* reg0 = (const float*)d_in[3];
  const float* reg1 = (const float*)d_in[4];
  const float* reg2 = (const float*)d_in[5];
  const float* obj0 = (const float*)d_in[6];
  const float* obj1 = (const float*)d_in[7];
  const float* obj2 = (const float*)d_in[8];

  char* w = (char*)d_ws;
  uint64_t* mask = (uint64_t*)w;  w += (size_t)NIMG * PTOT * NW * 8;  // 35,481,600 B
  uint64_t* keepw = (uint64_t*)w; w += (size_t)NIMG * NW * 8;
  float* score = (float*)w;       w += (size_t)NIMG * PTOT * 4;
  int*   label = (int*)w;         w += (size_t)NIMG * PTOT * 4;
  float* boxes = (float*)w;       w += (size_t)NIMG * PTOT * 16;
  float* ss = (float*)w;          w += (size_t)NIMG * PTOT * 4;
  int*   sl = (int*)w;            w += (size_t)NIMG * PTOT * 4;
  float* sb = (float*)w;          w += (size_t)NIMG * PTOT * 16;
  float* sq = (float*)w;          w += (size_t)NIMG * PTOT * 16;
  float* sa = (float*)w;          w += (size_t)NIMG * PTOT * 4;
  unsigned* gmax = (unsigned*)w;  w += 256;                            // 4 used, pad for align
  uint64_t* diag = (uint64_t*)w;  w += (size_t)NIMG * DSTR * 8;        // 270,336 B
  uint64_t* flags = (uint64_t*)w; w += (size_t)NIMG * NW * 8;          // 4,224 B
  int* nvalid = (int*)w;          w += 256;

  k_init<<<dim3(1), dim3(256), 0, stream>>>(gmax, flags, nvalid, diag);
  k_decode<<<dim3((NIMG * PTOT) / 64), dim3(64), 0, stream>>>(
      cls0, cls1, cls2, reg0, reg1, reg2, obj0, obj1, obj2,
      score, label, boxes, gmax);
  k_rank<<<dim3((PTOT + 255) / 256, NIMG), dim3(256), 0, stream>>>(
      score, label, boxes, gmax, nvalid, ss, sl, sb, sq, sa);
  k_mask<<<dim3(NW, NW, NIMG), dim3(64), 0, stream>>>(sq, sa, mask, diag, flags);
  k_scan<<<dim3(NIMG), dim3(64), 0, stream>>>(mask, diag, flags, nvalid, keepw);
  k_final<<<dim3((NIMG * PTOT + 255) / 256), dim3(256), 0, stream>>>(
      ss, sl, sb, keepw, (float*)d_out);
}

// Round 3
// 303.864 us; speedup vs baseline: 5.0565x; 1.4464x over previous
//
#include <hip/hip_runtime.h>
#include <stdint.h>

#define NIMG 4
#define PTOT 8400
#define NCLS 80
#define NW   132            // 64-bit words per mask row (ceil(8400/64))
#define DSTR (NW * 64)      // 8448: padded rows per image in diag array
#define JCH  16             // j-chunks for rank counting
#define JLEN (PTOT / JCH)   // 525
#define NMS_THR_C 0.65f
#define SCORE_THR_C 0.01f

static __device__ __forceinline__ float sigmoidf_(float x) {
  return 1.0f / (1.0f + expf(-x));
}
// order-preserving float->uint encoding for atomicMax
static __device__ __forceinline__ unsigned enc_f(float f) {
  unsigned u = __float_as_uint(f);
  return (u >> 31) ? ~u : (u | 0x80000000u);
}
static __device__ __forceinline__ float dec_f(unsigned e) {
  return (e >> 31) ? __uint_as_float(e ^ 0x80000000u) : __uint_as_float(~e);
}

__global__ void k_init(unsigned* gmax, uint64_t* flags, int* nvalid, uint64_t* diag,
                       int* rank) {
  int t = blockIdx.x * 256 + threadIdx.x;
  int NT = gridDim.x * 256;
  for (int k = t; k < NIMG * PTOT; k += NT) rank[k] = 0;
  for (int k = t; k < NIMG * NW; k += NT) flags[k] = 0ull;
  for (int k = t; k < NIMG * (DSTR - PTOT); k += NT) {
    int nn = k / (DSTR - PTOT), kk = k - nn * (DSTR - PTOT);
    diag[(size_t)nn * DSTR + PTOT + kk] = 0ull;
  }
  if (t < NIMG) { gmax[t] = 0u; nvalid[t] = 0; }
}

// ---------------- decode: sigmoid + argmax + box decode + per-image coord max
__global__ __launch_bounds__(64) void k_decode(
    const float* __restrict__ cls0, const float* __restrict__ cls1, const float* __restrict__ cls2,
    const float* __restrict__ reg0, const float* __restrict__ reg1, const float* __restrict__ reg2,
    const float* __restrict__ obj0, const float* __restrict__ obj1, const float* __restrict__ obj2,
    float* __restrict__ score, int* __restrict__ label, float* __restrict__ boxes,
    unsigned* __restrict__ gmax)
{
  int t = blockIdx.x * 64 + threadIdx.x;   // grid = 525*64 == 33600 exactly
  int n = t / PTOT;
  int p = t - n * PTOT;
  const float* cb; const float* rb; const float* ob;
  int HW, W, pl; float s;
  if (p < 6400)      { cb = cls0; rb = reg0; ob = obj0; HW = 6400; W = 80; pl = p;        s = 8.f;  }
  else if (p < 8000) { cb = cls1; rb = reg1; ob = obj1; HW = 1600; W = 40; pl = p - 6400; s = 16.f; }
  else               { cb = cls2; rb = reg2; ob = obj2; HW = 400;  W = 20; pl = p - 8000; s = 32.f; }

  // argmax over sigmoid(cls) — first max wins (replicates jnp.argmax on sigmoid values)
  const float* cp = cb + (size_t)n * NCLS * HW + pl;
  float best = -1.0f; int bi = 0;
  for (int c = 0; c < NCLS; ++c) {
    float v = sigmoidf_(cp[(size_t)c * HW]);
    if (v > best) { best = v; bi = c; }
  }
  float osg = sigmoidf_(ob[(size_t)n * HW + pl]);
  float sc = best * osg;

  const float* rp = rb + (size_t)n * 4 * HW + pl;
  float rx = rp[0], ry = rp[(size_t)HW], rw = rp[(size_t)2 * HW], rh = rp[(size_t)3 * HW];
  int ph = pl / W, pw = pl - ph * W;
  float px = (float)pw * s, py = (float)ph * s;
  float cx = rx * s + px, cy = ry * s + py;
  float bw = expf(rw) * s, bh = expf(rh) * s;
  float x1 = cx - bw * 0.5f, y1 = cy - bh * 0.5f;
  float x2 = cx + bw * 0.5f, y2 = cy + bh * 0.5f;

  score[t] = sc;
  label[t] = bi;
  float* bx = boxes + (size_t)t * 4;
  bx[0] = x1; bx[1] = y1; bx[2] = x2; bx[3] = y2;

  // per-image max over all box coords (for the class-offset trick)
  float m = fmaxf(fmaxf(x1, y1), fmaxf(x2, y2));
  unsigned long long samen = __ballot(n == __shfl(n, 0, 64));
  if (samen == ~0ull) {
    for (int o = 32; o; o >>= 1) m = fmaxf(m, __shfl_xor(m, o, 64));
    if (threadIdx.x == 0) atomicMax(&gmax[n], enc_f(m));
  } else {
    atomicMax(&gmax[n], enc_f(m));  // rare boundary waves
  }
}

// ---------------- stable descending rank: partial counts over j-chunks
__global__ __launch_bounds__(256) void k_count(
    const float* __restrict__ score, int* __restrict__ rank)
{
  __shared__ float keys[JLEN];
  int n = blockIdx.z, jc = blockIdx.y;
  int tid = threadIdx.x;
  int j0 = jc * JLEN;
  const float* sc = score + (size_t)n * PTOT;
  for (int j = tid; j < JLEN; j += 256) {
    float v = sc[j0 + j];
    keys[j] = (v >= SCORE_THR_C) ? v : -1.0f;
  }
  __syncthreads();
  int i = blockIdx.x * 256 + tid;
  if (i >= PTOT) return;
  float vi = sc[i];
  float ki = (vi >= SCORE_THR_C) ? vi : -1.0f;
  int cnt = 0;
#pragma unroll 5
  for (int j = 0; j < JLEN; ++j) {
    float kj = keys[j];
    int jg = j0 + j;
    cnt += (int)(kj > ki) + (int)((kj == ki) && (jg < i));
  }
  if (cnt) atomicAdd(&rank[(size_t)n * PTOT + i], cnt);
}

// ---------------- scatter into sorted order + shifted boxes/areas + nvalid
__global__ __launch_bounds__(256) void k_scatter(
    const float* __restrict__ score, const int* __restrict__ label, const float* __restrict__ boxes,
    const unsigned* __restrict__ gmax, const int* __restrict__ rank, int* __restrict__ nvalid,
    float* __restrict__ s_score, int* __restrict__ s_label,
    float* __restrict__ s_box, float* __restrict__ s_sbox, float* __restrict__ s_area)
{
  int n = blockIdx.y;
  int i = blockIdx.x * 256 + threadIdx.x;
  if (i >= PTOT) return;
  const float* sc = score + (size_t)n * PTOT;
  float v = sc[i];
  bool valid = (v >= SCORE_THR_C);
  unsigned long long bal = __ballot(valid);
  if ((threadIdx.x & 63) == 0) atomicAdd(&nvalid[n], (int)__popcll(bal));

  int r = rank[(size_t)n * PTOT + i];  // stable permutation
  float gm = dec_f(gmax[n]);
  int li = label[(size_t)n * PTOT + i];
  const float* bp = boxes + ((size_t)n * PTOT + i) * 4;
  float b0 = bp[0], b1 = bp[1], b2 = bp[2], b3 = bp[3];
  float off = (float)li * (gm + 1.0f);
  float q0 = b0 + off, q1 = b1 + off, q2 = b2 + off, q3 = b3 + off;
  float area = (q2 - q0) * (q3 - q1);   // area from SHIFTED coords (matches reference)

  size_t d = (size_t)n * PTOT + (size_t)r;
  s_score[d] = v;
  s_label[d] = li;
  float* sb = s_box + d * 4;  sb[0] = b0; sb[1] = b1; sb[2] = b2; sb[3] = b3;
  float* sq = s_sbox + d * 4; sq[0] = q0; sq[1] = q1; sq[2] = q2; sq[3] = q3;
  s_area[d] = area;
}

// ---------------- pairwise IoU suppression bitmask (upper triangle, 64x64 tiles)
// c == r: write compact diag word. c > r: write mask row word + row-nonzero flag.
__global__ __launch_bounds__(64) void k_mask(
    const float* __restrict__ s_sbox, const float* __restrict__ s_area,
    uint64_t* __restrict__ mask, uint64_t* __restrict__ diag, uint64_t* __restrict__ flags)
{
  int c = blockIdx.x, r = blockIdx.y, n = blockIdx.z;
  if (c < r) return;  // whole block uniform exit (no barrier executed)
  int l = threadIdx.x;
  __shared__ float cbx[64], cby[64], cbX[64], cbY[64], cba[64];
  int j = c * 64 + l;
  if (j < PTOT) {
    const float* q = s_sbox + ((size_t)n * PTOT + j) * 4;
    cbx[l] = q[0]; cby[l] = q[1]; cbX[l] = q[2]; cbY[l] = q[3];
    cba[l] = s_area[(size_t)n * PTOT + j];
  } else {
    cbx[l] = 0.f; cby[l] = 0.f; cbX[l] = 0.f; cbY[l] = 0.f; cba[l] = 0.f;
  }
  __syncthreads();
  int i = r * 64 + l;
  float ax1 = 0.f, ay1 = 0.f, ax2 = 0.f, ay2 = 0.f, aa = 0.f;
  if (i < PTOT) {
    const float* q = s_sbox + ((size_t)n * PTOT + i) * 4;
    ax1 = q[0]; ay1 = q[1]; ax2 = q[2]; ay2 = q[3];
    aa = s_area[(size_t)n * PTOT + i];
  }
  uint64_t w = 0;
#pragma unroll 4
  for (int jj = 0; jj < 64; ++jj) {
    float ltx = fmaxf(ax1, cbx[jj]);
    float lty = fmaxf(ay1, cby[jj]);
    float rbx = fminf(ax2, cbX[jj]);
    float rby = fminf(ay2, cbY[jj]);
    float ww = fmaxf(rbx - ltx, 0.0f);
    float hh = fmaxf(rby - lty, 0.0f);
    float inter = ww * hh;
    float uni = fmaxf(aa + cba[jj] - inter, 1e-12f);
    float iou = inter / uni;           // real division to match reference rounding
    int jg = c * 64 + jj;
    bool bit = (iou > NMS_THR_C) && (jg > i) && (jg < PTOT);
    w |= ((uint64_t)bit) << jj;
  }
  bool realrow = (i < PTOT);
  if (c == r) {
    if (realrow) diag[(size_t)n * DSTR + i] = w;
  } else {
    if (realrow) mask[((size_t)n * PTOT + (size_t)i) * NW + c] = w;
    unsigned long long bal = __ballot(realrow && (w != 0ull));
    if (l == 0 && bal) atomicOr((unsigned long long*)&flags[(size_t)n * NW + r], bal);
  }
}

// ---------------- greedy suppression scan: 1 wave per image, sparse chunk walk
__global__ __launch_bounds__(64) void k_scan(
    const uint64_t* __restrict__ mask,
    const uint64_t* __restrict__ diag,
    const uint64_t* __restrict__ flags,
    const int* __restrict__ nvalid,
    uint64_t* __restrict__ keepw)
{
  int n = blockIdx.x, l = threadIdx.x;
  int nv = nvalid[n];

  // removed-mask init: sorted order puts invalid boxes last -> removed = bits >= nv
  // lane l owns words l, 64+l, (l<4: 128+l)
  auto initw = [&](int w) -> uint64_t {
    int base = w * 64;
    if (nv <= base) return ~0ull;
    if (nv >= base + 64) return 0ull;
    return (~0ull) << (nv - base);
  };
  uint64_t r0 = initw(l), r1 = initw(64 + l), r2 = (l < 4) ? initw(128 + l) : 0ull;

  const uint64_t* fl = flags + (size_t)n * NW;
  uint64_t f0 = fl[l], f1 = fl[64 + l], f2 = (l < 4) ? fl[128 + l] : 0ull;
  const uint64_t* dg = diag + (size_t)n * DSTR;
  const uint64_t* mrow = mask + (size_t)n * PTOT * NW;

  // diag word prefetch, depth 2 (lane l holds row c*64+l's in-chunk word)
  uint64_t dcur = dg[l];
  uint64_t dnxt = dg[64 + l];

  for (int c = 0; c < NW; ++c) {
    uint64_t d = dcur;
    dcur = dnxt;
    if (c + 2 < NW) dnxt = dg[(size_t)(c + 2) * 64 + l];

    int ol = c & 63;  // owner lane of word c in its slot
    uint64_t srcw = (c < 64) ? r0 : ((c < 128) ? r1 : r2);
    uint64_t R = __shfl(srcw, ol, 64);          // removed word for this chunk (uniform)
    uint64_t fsrc = (c < 64) ? f0 : ((c < 128) ? f1 : f2);
    uint64_t F = __shfl(fsrc, ol, 64);          // rows with off-diag suppression bits

    // in-chunk greedy resolve: only rows with nonzero diag words matter
    uint64_t nz = __ballot(d != 0ull);
    uint64_t pending = nz & ~R;
    while (pending) {
      int b = __builtin_ctzll(pending);
      uint64_t row = __shfl(d, b, 64);          // bits only for j>b within chunk
      R |= row;
      pending &= ~R;
      pending &= pending - 1;                    // clear bit b (still lowest)
    }
    if (l == ol) { if (c < 64) r0 = R; else if (c < 128) r1 = R; else r2 = R; }

    // OR full rows of kept+flagged boxes into future removed words (word > c only)
    uint64_t kf = F & ~R;
    uint64_t m0 = (l > c) ? ~0ull : 0ull;
    uint64_t m1 = (64 + l > c) ? ~0ull : 0ull;
    uint64_t m2 = (128 + l > c) ? ~0ull : 0ull;
    while (kf) {
      int b1 = __builtin_ctzll(kf); kf &= kf - 1;
      const uint64_t* rp1 = mrow + (size_t)(c * 64 + b1) * NW;
      uint64_t a0 = rp1[l], a1 = rp1[64 + l], a2 = (l < 4) ? rp1[128 + l] : 0ull;
      if (kf) {  // 2-way unroll to overlap load latency
        int b2 = __builtin_ctzll(kf); kf &= kf - 1;
        const uint64_t* rp2 = mrow + (size_t)(c * 64 + b2) * NW;
        uint64_t c0 = rp2[l], c1 = rp2[64 + l], c2 = (l < 4) ? rp2[128 + l] : 0ull;
        a0 |= c0; a1 |= c1; a2 |= c2;
      }
      r0 |= a0 & m0;
      r1 |= a1 & m1;
      if (l < 4) r2 |= a2 & m2;
    }
  }

  keepw[(size_t)n * NW + l] = ~r0;
  keepw[(size_t)n * NW + 64 + l] = ~r1;
  if (l < 4) keepw[(size_t)n * NW + 128 + l] = ~r2;
}

// ---------------- finalize outputs
__global__ __launch_bounds__(256) void k_final(
    const float* __restrict__ s_score, const int* __restrict__ s_label,
    const float* __restrict__ s_box, const uint64_t* __restrict__ keepw,
    float* __restrict__ out)
{
  int t = blockIdx.x * 256 + threadIdx.x;
  if (t >= NIMG * PTOT) return;
  int n = t / PTOT, p = t - n * PTOT;
  uint64_t w = keepw[(size_t)n * NW + (p >> 6)];
  float k = (float)((w >> (p & 63)) & 1ull);
  float* dets = out;
  float* lab  = out + (size_t)NIMG * PTOT * 5;
  float* kp   = out + (size_t)NIMG * PTOT * 6;
  const float* bp = s_box + (size_t)t * 4;
  float* dp = dets + (size_t)t * 5;
  dp[0] = bp[0] * k; dp[1] = bp[1] * k; dp[2] = bp[2] * k; dp[3] = bp[3] * k;
  dp[4] = s_score[t] * k;
  lab[t] = (float)s_label[t];
  kp[t]  = k;
}

extern "C" void kernel_launch(void* const* d_in, const int* in_sizes, int n_in,
                              void* d_out, int out_size, void* d_ws, size_t ws_size,
                              hipStream_t stream)
{
  const float* cls0 = (const float*)d_in[0];
  const float* cls1 = (const float*)d_in[1];
  const float* cls2 = (const float*)d_in[2];
  const float* reg0 = (const float*)d_in[3];
  const float* reg1 = (const float*)d_in[4];
  const float* reg2 = (const float*)d_in[5];
  const float* obj0 = (const float*)d_in[6];
  const float* obj1 = (const float*)d_in[7];
  const float* obj2 = (const float*)d_in[8];

  char* w = (char*)d_ws;
  uint64_t* mask = (uint64_t*)w;  w += (size_t)NIMG * PTOT * NW * 8;  // 35,481,600 B
  uint64_t* keepw = (uint64_t*)w; w += (size_t)NIMG * NW * 8;
  float* score = (float*)w;       w += (size_t)NIMG * PTOT * 4;
  int*   label = (int*)w;         w += (size_t)NIMG * PTOT * 4;
  float* boxes = (float*)w;       w += (size_t)NIMG * PTOT * 16;
  float* ss = (float*)w;          w += (size_t)NIMG * PTOT * 4;
  int*   sl = (int*)w;            w += (size_t)NIMG * PTOT * 4;
  float* sb = (float*)w;          w += (size_t)NIMG * PTOT * 16;
  float* sq = (float*)w;          w += (size_t)NIMG * PTOT * 16;
  float* sa = (float*)w;          w += (size_t)NIMG * PTOT * 4;
  unsigned* gmax = (unsigned*)w;  w += 256;                            // 4 used, pad for align
  uint64_t* diag = (uint64_t*)w;  w += (size_t)NIMG * DSTR * 8;        // 270,336 B
  uint64_t* flags = (uint64_t*)w; w += (size_t)NIMG * NW * 8;          // 4,224 B
  int* nvalid = (int*)w;          w += 256;
  int* rank = (int*)w;            w += (size_t)NIMG * PTOT * 4;

  k_init<<<dim3(64), dim3(256), 0, stream>>>(gmax, flags, nvalid, diag, rank);
  k_decode<<<dim3((NIMG * PTOT) / 64), dim3(64), 0, stream>>>(
      cls0, cls1, cls2, reg0, reg1, reg2, obj0, obj1, obj2,
      score, label, boxes, gmax);
  k_count<<<dim3((PTOT + 255) / 256, JCH, NIMG), dim3(256), 0, stream>>>(score, rank);
  k_scatter<<<dim3((PTOT + 255) / 256, NIMG), dim3(256), 0, stream>>>(
      score, label, boxes, gmax, rank, nvalid, ss, sl, sb, sq, sa);
  k_mask<<<dim3(NW, NW, NIMG), dim3(64), 0, stream>>>(sq, sa, mask, diag, flags);
  k_scan<<<dim3(NIMG), dim3(64), 0, stream>>>(mask, diag, flags, nvalid, keepw);
  k_final<<<dim3((NIMG * PTOT + 255) / 256), dim3(256), 0, stream>>>(
      ss, sl, sb, keepw, (float*)d_out);
}

// Round 4
// 273.118 us; speedup vs baseline: 5.6257x; 1.1126x over previous
//
#include <hip/hip_runtime.h>
#include <stdint.h>

#define NIMG 4
#define PTOT 8400
#define NCLS 80
#define NW   132            // 64-bit words per mask row (ceil(8400/64))
#define DSTR (NW * 64)      // 8448: padded rows per image in diag array
#define JCH  16             // j-chunks for rank counting
#define JLEN (PTOT / JCH)   // 525
#define DMAX 3              // max label distance with possible slab overlap (provably safe)
#define NMS_THR_C 0.65f
#define SCORE_THR_C 0.01f

static __device__ __forceinline__ float sigmoidf_(float x) {
  return 1.0f / (1.0f + expf(-x));
}
// order-preserving float->uint encoding for atomicMax
static __device__ __forceinline__ unsigned enc_f(float f) {
  unsigned u = __float_as_uint(f);
  return (u >> 31) ? ~u : (u | 0x80000000u);
}
static __device__ __forceinline__ float dec_f(unsigned e) {
  return (e >> 31) ? __uint_as_float(e ^ 0x80000000u) : __uint_as_float(~e);
}

__global__ void k_init(unsigned* gmax, uint64_t* flags, int* nvalid, uint64_t* diag,
                       int* rank, int* hist, uint4* mask4) {
  int t = blockIdx.x * 256 + threadIdx.x;
  int NT = gridDim.x * 256;
  // mask zero-fill: 35,481,600 B = 2,217,600 uint4
  const int M4 = NIMG * PTOT * NW / 2;  // (PTOT*NW words *8B)/16B
  for (int k = t; k < M4; k += NT) mask4[k] = make_uint4(0, 0, 0, 0);
  for (int k = t; k < NIMG * DSTR; k += NT) diag[k] = 0ull;
  for (int k = t; k < NIMG * PTOT; k += NT) rank[k] = 0;
  for (int k = t; k < NIMG * NW; k += NT) flags[k] = 0ull;
  for (int k = t; k < NIMG * NCLS; k += NT) hist[k] = 0;
  if (t < NIMG) { gmax[t] = 0u; nvalid[t] = 0; }
}

// ---------------- decode: sigmoid + argmax + box decode + per-image coord max
__global__ __launch_bounds__(64) void k_decode(
    const float* __restrict__ cls0, const float* __restrict__ cls1, const float* __restrict__ cls2,
    const float* __restrict__ reg0, const float* __restrict__ reg1, const float* __restrict__ reg2,
    const float* __restrict__ obj0, const float* __restrict__ obj1, const float* __restrict__ obj2,
    float* __restrict__ score, int* __restrict__ label, float* __restrict__ boxes,
    unsigned* __restrict__ gmax)
{
  int t = blockIdx.x * 64 + threadIdx.x;   // grid = 525*64 == 33600 exactly
  int n = t / PTOT;
  int p = t - n * PTOT;
  const float* cb; const float* rb; const float* ob;
  int HW, W, pl; float s;
  if (p < 6400)      { cb = cls0; rb = reg0; ob = obj0; HW = 6400; W = 80; pl = p;        s = 8.f;  }
  else if (p < 8000) { cb = cls1; rb = reg1; ob = obj1; HW = 1600; W = 40; pl = p - 6400; s = 16.f; }
  else               { cb = cls2; rb = reg2; ob = obj2; HW = 400;  W = 20; pl = p - 8000; s = 32.f; }

  // argmax over sigmoid(cls) — first max wins (replicates jnp.argmax on sigmoid values)
  const float* cp = cb + (size_t)n * NCLS * HW + pl;
  float best = -1.0f; int bi = 0;
  for (int c = 0; c < NCLS; ++c) {
    float v = sigmoidf_(cp[(size_t)c * HW]);
    if (v > best) { best = v; bi = c; }
  }
  float osg = sigmoidf_(ob[(size_t)n * HW + pl]);
  float sc = best * osg;

  const float* rp = rb + (size_t)n * 4 * HW + pl;
  float rx = rp[0], ry = rp[(size_t)HW], rw = rp[(size_t)2 * HW], rh = rp[(size_t)3 * HW];
  int ph = pl / W, pw = pl - ph * W;
  float px = (float)pw * s, py = (float)ph * s;
  float cx = rx * s + px, cy = ry * s + py;
  float bw = expf(rw) * s, bh = expf(rh) * s;
  float x1 = cx - bw * 0.5f, y1 = cy - bh * 0.5f;
  float x2 = cx + bw * 0.5f, y2 = cy + bh * 0.5f;

  score[t] = sc;
  label[t] = bi;
  float* bx = boxes + (size_t)t * 4;
  bx[0] = x1; bx[1] = y1; bx[2] = x2; bx[3] = y2;

  // per-image max over all box coords (for the class-offset trick)
  float m = fmaxf(fmaxf(x1, y1), fmaxf(x2, y2));
  unsigned long long samen = __ballot(n == __shfl(n, 0, 64));
  if (samen == ~0ull) {
    for (int o = 32; o; o >>= 1) m = fmaxf(m, __shfl_xor(m, o, 64));
    if (threadIdx.x == 0) atomicMax(&gmax[n], enc_f(m));
  } else {
    atomicMax(&gmax[n], enc_f(m));  // rare boundary waves
  }
}

// ---------------- stable descending rank: partial counts over j-chunks
__global__ __launch_bounds__(256) void k_count(
    const float* __restrict__ score, int* __restrict__ rank)
{
  __shared__ float keys[JLEN];
  int n = blockIdx.z, jc = blockIdx.y;
  int tid = threadIdx.x;
  int j0 = jc * JLEN;
  const float* sc = score + (size_t)n * PTOT;
  for (int j = tid; j < JLEN; j += 256) {
    float v = sc[j0 + j];
    keys[j] = (v >= SCORE_THR_C) ? v : -1.0f;
  }
  __syncthreads();
  int i = blockIdx.x * 256 + tid;
  if (i >= PTOT) return;
  float vi = sc[i];
  float ki = (vi >= SCORE_THR_C) ? vi : -1.0f;
  int cnt = 0;
#pragma unroll 5
  for (int j = 0; j < JLEN; ++j) {
    float kj = keys[j];
    int jg = j0 + j;
    cnt += (int)(kj > ki) + (int)((kj == ki) && (jg < i));
  }
  if (cnt) atomicAdd(&rank[(size_t)n * PTOT + i], cnt);
}

// ---------------- scatter into sorted order + shifted boxes/areas + nvalid + label hist
__global__ __launch_bounds__(256) void k_scatter(
    const float* __restrict__ score, const int* __restrict__ label, const float* __restrict__ boxes,
    const unsigned* __restrict__ gmax, const int* __restrict__ rank, int* __restrict__ nvalid,
    float* __restrict__ s_score, int* __restrict__ s_label,
    float* __restrict__ s_box, float* __restrict__ s_sbox, float* __restrict__ s_area,
    int* __restrict__ hist)
{
  int n = blockIdx.y;
  int i = blockIdx.x * 256 + threadIdx.x;
  if (i >= PTOT) return;
  const float* sc = score + (size_t)n * PTOT;
  float v = sc[i];
  bool valid = (v >= SCORE_THR_C);
  unsigned long long bal = __ballot(valid);
  if ((threadIdx.x & 63) == 0) atomicAdd(&nvalid[n], (int)__popcll(bal));

  int r = rank[(size_t)n * PTOT + i];  // stable permutation
  float gm = dec_f(gmax[n]);
  int li = label[(size_t)n * PTOT + i];
  atomicAdd(&hist[n * NCLS + li], 1);
  const float* bp = boxes + ((size_t)n * PTOT + i) * 4;
  float b0 = bp[0], b1 = bp[1], b2 = bp[2], b3 = bp[3];
  float off = (float)li * (gm + 1.0f);
  float q0 = b0 + off, q1 = b1 + off, q2 = b2 + off, q3 = b3 + off;
  float area = (q2 - q0) * (q3 - q1);   // area from SHIFTED coords (matches reference)

  size_t d = (size_t)n * PTOT + (size_t)r;
  s_score[d] = v;
  s_label[d] = li;
  float* sb = s_box + d * 4;  sb[0] = b0; sb[1] = b1; sb[2] = b2; sb[3] = b3;
  float* sq = s_sbox + d * 4; sq[0] = q0; sq[1] = q1; sq[2] = q2; sq[3] = q3;
  s_area[d] = area;
}

// ---------------- bucket scan: exclusive scan of label histogram per image
__global__ void k_bscan(const int* __restrict__ hist, int* __restrict__ bstart,
                        int* __restrict__ cursor)
{
  int n = blockIdx.x;
  if (threadIdx.x == 0) {
    int acc = 0;
    for (int L = 0; L < NCLS; ++L) { bstart[n * (NCLS + 1) + L] = acc; acc += hist[n * NCLS + L]; }
    bstart[n * (NCLS + 1) + NCLS] = acc;
  }
  __syncthreads();
  for (int L = threadIdx.x; L < NCLS; L += blockDim.x)
    cursor[n * NCLS + L] = bstart[n * (NCLS + 1) + L];
}

// ---------------- bucket fill: sorted position -> its label bucket
__global__ __launch_bounds__(256) void k_bfill(
    const int* __restrict__ s_label, int* __restrict__ cursor, int* __restrict__ bidx)
{
  int t = blockIdx.x * 256 + threadIdx.x;
  if (t >= NIMG * PTOT) return;
  int n = t / PTOT, r = t - n * PTOT;
  int L = s_label[t];
  int pos = atomicAdd(&cursor[n * NCLS + L], 1);
  bidx[(size_t)n * PTOT + pos] = r;
}

// ---------------- sparse pair IoU: same-label + up-to-DMAX-adjacent-label pairs
// (class-offset slabs make farther labels provably non-overlapping)
__global__ __launch_bounds__(256) void k_pairs(
    const float* __restrict__ s_sbox, const float* __restrict__ s_area,
    const int* __restrict__ bstart, const int* __restrict__ bidx,
    uint64_t* __restrict__ mask, uint64_t* __restrict__ diag, uint64_t* __restrict__ flags)
{
  int n = blockIdx.z, L = blockIdx.x, d = blockIdx.y;
  int L2 = L + d;
  if (L2 >= NCLS) return;
  const int* bs = bstart + n * (NCLS + 1);
  int a0 = bs[L], a1 = bs[L + 1];
  int b0 = bs[L2], b1 = bs[L2 + 1];
  int na = a1 - a0, nb = b1 - b0;
  if (na == 0 || nb == 0) return;
  const int* ba = bidx + (size_t)n * PTOT + a0;
  const int* bb = bidx + (size_t)n * PTOT + b0;
  const float4* SB = (const float4*)(s_sbox + (size_t)n * PTOT * 4);
  const float* SA = s_area + (size_t)n * PTOT;
  int tot = na * nb;
  for (int t = threadIdx.x; t < tot; t += 256) {
    int u = t / nb, v = t - u * nb;
    if (d == 0 && u >= v) continue;          // unordered within-bucket pairs
    int p = ba[u], q = bb[v];
    float4 A = SB[p], B = SB[q];
    float ww = fminf(A.z, B.z) - fmaxf(A.x, B.x);
    float hh = fminf(A.w, B.w) - fmaxf(A.y, B.y);
    if (ww <= 0.0f || hh <= 0.0f) continue;  // inter=0 -> iou=0 -> no bit (exact)
    float inter = ww * hh;                   // == clip(ww)*clip(hh) here
    float aa = SA[p], ab = SA[q];
    float uni = fmaxf(aa + ab - inter, 1e-12f);
    if (inter / uni > NMS_THR_C) {           // identical arithmetic to reference
      int i = min(p, q), j = max(p, q);
      int iw = i >> 6, jw = j >> 6;
      if (iw == jw) {
        atomicOr((unsigned long long*)&diag[(size_t)n * DSTR + i], 1ull << (j & 63));
      } else {
        atomicOr((unsigned long long*)&mask[((size_t)n * PTOT + i) * NW + jw], 1ull << (j & 63));
        atomicOr((unsigned long long*)&flags[(size_t)n * NW + iw], 1ull << (i & 63));
      }
    }
  }
}

// ---------------- greedy suppression scan: 1 wave per image, sparse chunk walk
__global__ __launch_bounds__(64) void k_scan(
    const uint64_t* __restrict__ mask,
    const uint64_t* __restrict__ diag,
    const uint64_t* __restrict__ flags,
    const int* __restrict__ nvalid,
    uint64_t* __restrict__ keepw)
{
  int n = blockIdx.x, l = threadIdx.x;
  int nv = nvalid[n];

  // removed-mask init: sorted order puts invalid boxes last -> removed = bits >= nv
  // lane l owns words l, 64+l, (l<4: 128+l)
  auto initw = [&](int w) -> uint64_t {
    int base = w * 64;
    if (nv <= base) return ~0ull;
    if (nv >= base + 64) return 0ull;
    return (~0ull) << (nv - base);
  };
  uint64_t r0 = initw(l), r1 = initw(64 + l), r2 = (l < 4) ? initw(128 + l) : 0ull;

  const uint64_t* fl = flags + (size_t)n * NW;
  uint64_t f0 = fl[l], f1 = fl[64 + l], f2 = (l < 4) ? fl[128 + l] : 0ull;
  const uint64_t* dg = diag + (size_t)n * DSTR;
  const uint64_t* mrow = mask + (size_t)n * PTOT * NW;

  // diag word prefetch, depth 2 (lane l holds row c*64+l's in-chunk word)
  uint64_t dcur = dg[l];
  uint64_t dnxt = dg[64 + l];

  for (int c = 0; c < NW; ++c) {
    uint64_t d = dcur;
    dcur = dnxt;
    if (c + 2 < NW) dnxt = dg[(size_t)(c + 2) * 64 + l];

    int ol = c & 63;  // owner lane of word c in its slot
    uint64_t srcw = (c < 64) ? r0 : ((c < 128) ? r1 : r2);
    uint64_t R = __shfl(srcw, ol, 64);          // removed word for this chunk (uniform)
    uint64_t fsrc = (c < 64) ? f0 : ((c < 128) ? f1 : f2);
    uint64_t F = __shfl(fsrc, ol, 64);          // rows with off-diag suppression bits

    // in-chunk greedy resolve: only rows with nonzero diag words matter
    uint64_t nz = __ballot(d != 0ull);
    uint64_t pending = nz & ~R;
    while (pending) {
      int b = __builtin_ctzll(pending);
      uint64_t row = __shfl(d, b, 64);          // bits only for j>b within chunk
      R |= row;
      pending &= ~R;
      pending &= pending - 1;                    // clear bit b (still lowest)
    }
    if (l == ol) { if (c < 64) r0 = R; else if (c < 128) r1 = R; else r2 = R; }

    // OR full rows of kept+flagged boxes into future removed words (word > c only)
    uint64_t kf = F & ~R;
    uint64_t m0 = (l > c) ? ~0ull : 0ull;
    uint64_t m1 = (64 + l > c) ? ~0ull : 0ull;
    uint64_t m2 = (128 + l > c) ? ~0ull : 0ull;
    while (kf) {
      int b1 = __builtin_ctzll(kf); kf &= kf - 1;
      const uint64_t* rp1 = mrow + (size_t)(c * 64 + b1) * NW;
      uint64_t a0 = rp1[l], a1 = rp1[64 + l], a2 = (l < 4) ? rp1[128 + l] : 0ull;
      if (kf) {  // 2-way unroll to overlap load latency
        int b2 = __builtin_ctzll(kf); kf &= kf - 1;
        const uint64_t* rp2 = mrow + (size_t)(c * 64 + b2) * NW;
        uint64_t c0 = rp2[l], c1 = rp2[64 + l], c2 = (l < 4) ? rp2[128 + l] : 0ull;
        a0 |= c0; a1 |= c1; a2 |= c2;
      }
      r0 |= a0 & m0;
      r1 |= a1 & m1;
      if (l < 4) r2 |= a2 & m2;
    }
  }

  keepw[(size_t)n * NW + l] = ~r0;
  keepw[(size_t)n * NW + 64 + l] = ~r1;
  if (l < 4) keepw[(size_t)n * NW + 128 + l] = ~r2;
}

// ---------------- finalize outputs
__global__ __launch_bounds__(256) void k_final(
    const float* __restrict__ s_score, const int* __restrict__ s_label,
    const float* __restrict__ s_box, const uint64_t* __restrict__ keepw,
    float* __restrict__ out)
{
  int t = blockIdx.x * 256 + threadIdx.x;
  if (t >= NIMG * PTOT) return;
  int n = t / PTOT, p = t - n * PTOT;
  uint64_t w = keepw[(size_t)n * NW + (p >> 6)];
  float k = (float)((w >> (p & 63)) & 1ull);
  float* dets = out;
  float* lab  = out + (size_t)NIMG * PTOT * 5;
  float* kp   = out + (size_t)NIMG * PTOT * 6;
  const float* bp = s_box + (size_t)t * 4;
  float* dp = dets + (size_t)t * 5;
  dp[0] = bp[0] * k; dp[1] = bp[1] * k; dp[2] = bp[2] * k; dp[3] = bp[3] * k;
  dp[4] = s_score[t] * k;
  lab[t] = (float)s_label[t];
  kp[t]  = k;
}

extern "C" void kernel_launch(void* const* d_in, const int* in_sizes, int n_in,
                              void* d_out, int out_size, void* d_ws, size_t ws_size,
                              hipStream_t stream)
{
  const float* cls0 = (const float*)d_in[0];
  const float* cls1 = (const float*)d_in[1];
  const float* cls2 = (const float*)d_in[2];
  const float* reg0 = (const float*)d_in[3];
  const float* reg1 = (const float*)d_in[4];
  const float* reg2 = (const float*)d_in[5];
  const float* obj0 = (const float*)d_in[6];
  const float* obj1 = (const float*)d_in[7];
  const float* obj2 = (const float*)d_in[8];

  char* w = (char*)d_ws;
  uint64_t* mask = (uint64_t*)w;  w += (size_t)NIMG * PTOT * NW * 8;  // 35,481,600 B
  uint64_t* keepw = (uint64_t*)w; w += (size_t)NIMG * NW * 8;
  float* score = (float*)w;       w += (size_t)NIMG * PTOT * 4;
  int*   label = (int*)w;         w += (size_t)NIMG * PTOT * 4;
  float* boxes = (float*)w;       w += (size_t)NIMG * PTOT * 16;
  float* ss = (float*)w;          w += (size_t)NIMG * PTOT * 4;
  int*   sl = (int*)w;            w += (size_t)NIMG * PTOT * 4;
  float* sb = (float*)w;          w += (size_t)NIMG * PTOT * 16;
  float* sq = (float*)w;          w += (size_t)NIMG * PTOT * 16;
  float* sa = (float*)w;          w += (size_t)NIMG * PTOT * 4;
  unsigned* gmax = (unsigned*)w;  w += 256;                            // 4 used, pad for align
  uint64_t* diag = (uint64_t*)w;  w += (size_t)NIMG * DSTR * 8;        // 270,336 B
  uint64_t* flags = (uint64_t*)w; w += (size_t)NIMG * NW * 8;          // 4,224 B
  int* nvalid = (int*)w;          w += 256;
  int* rank = (int*)w;            w += (size_t)NIMG * PTOT * 4;
  int* hist = (int*)w;            w += (size_t)NIMG * NCLS * 4;        // 1,280 B
  int* bstart = (int*)w;          w += (size_t)NIMG * (NCLS + 1) * 4;  // 1,296 B
  int* cursor = (int*)w;          w += (size_t)NIMG * NCLS * 4;
  int* bidx = (int*)w;            w += (size_t)NIMG * PTOT * 4;

  k_init<<<dim3(512), dim3(256), 0, stream>>>(gmax, flags, nvalid, diag, rank, hist,
                                              (uint4*)mask);
  k_decode<<<dim3((NIMG * PTOT) / 64), dim3(64), 0, stream>>>(
      cls0, cls1, cls2, reg0, reg1, reg2, obj0, obj1, obj2,
      score, label, boxes, gmax);
  k_count<<<dim3((PTOT + 255) / 256, JCH, NIMG), dim3(256), 0, stream>>>(score, rank);
  k_scatter<<<dim3((PTOT + 255) / 256, NIMG), dim3(256), 0, stream>>>(
      score, label, boxes, gmax, rank, nvalid, ss, sl, sb, sq, sa, hist);
  k_bscan<<<dim3(NIMG), dim3(128), 0, stream>>>(hist, bstart, cursor);
  k_bfill<<<dim3((NIMG * PTOT + 255) / 256), dim3(256), 0, stream>>>(sl, cursor, bidx);
  k_pairs<<<dim3(NCLS, DMAX + 1, NIMG), dim3(256), 0, stream>>>(
      sq, sa, bstart, bidx, mask, diag, flags);
  k_scan<<<dim3(NIMG), dim3(64), 0, stream>>>(mask, diag, flags, nvalid, keepw);
  k_final<<<dim3((NIMG * PTOT + 255) / 256), dim3(256), 0, stream>>>(
      ss, sl, sb, keepw, (float*)d_out);
}

// Round 7
// 265.331 us; speedup vs baseline: 5.7908x; 1.0293x over previous
//
#include <hip/hip_runtime.h>
#include <stdint.h>

#define NIMG 4
#define PTOT 8400
#define NCLS 80
#define NW   132            // 64-bit words per mask row (ceil(8400/64))
#define DSTR (NW * 64)      // 8448: padded rows per image in diag array
#define DMAX 3              // max label distance with possible slab overlap (provably safe)
#define NMS_THR_C 0.65f
#define SCORE_THR_C 0.01f

static __device__ __forceinline__ float sigmoidf_(float x) {
  return 1.0f / (1.0f + expf(-x));
}
// order-preserving float->uint encoding for atomicMax
static __device__ __forceinline__ unsigned enc_f(float f) {
  unsigned u = __float_as_uint(f);
  return (u >> 31) ? ~u : (u | 0x80000000u);
}
static __device__ __forceinline__ float dec_f(unsigned e) {
  return (e >> 31) ? __uint_as_float(e ^ 0x80000000u) : __uint_as_float(~e);
}

__global__ void k_init(unsigned* gmax, uint64_t* flags, int* nvalid, uint64_t* diag,
                       int* lhist, uint4* mask4) {
  int t = blockIdx.x * 256 + threadIdx.x;
  int NT = gridDim.x * 256;
  // mask zero-fill: 35,481,600 B = 2,217,600 uint4 (atomicOr targets MUST start at 0:
  // harness poisons ws with 0xAA before every launch)
  const int M4 = NIMG * PTOT * NW / 2;
  for (int k = t; k < M4; k += NT) mask4[k] = make_uint4(0, 0, 0, 0);
  for (int k = t; k < NIMG * DSTR; k += NT) diag[k] = 0ull;
  for (int k = t; k < NIMG * NW; k += NT) flags[k] = 0ull;
  for (int k = t; k < NIMG * NCLS; k += NT) lhist[k] = 0;
  if (t < NIMG) { gmax[t] = 0u; nvalid[t] = 0; }
}

// ---------------- decode: sigmoid + argmax + box decode + coord max + label hist
__global__ __launch_bounds__(64) void k_decode(
    const float* __restrict__ cls0, const float* __restrict__ cls1, const float* __restrict__ cls2,
    const float* __restrict__ reg0, const float* __restrict__ reg1, const float* __restrict__ reg2,
    const float* __restrict__ obj0, const float* __restrict__ obj1, const float* __restrict__ obj2,
    float* __restrict__ score, int* __restrict__ label, float* __restrict__ boxes,
    unsigned* __restrict__ gmax, int* __restrict__ lhist)
{
  int t = blockIdx.x * 64 + threadIdx.x;   // grid = 525*64 == 33600 exactly
  int n = t / PTOT;
  int p = t - n * PTOT;
  const float* cb; const float* rb; const float* ob;
  int HW, W, pl; float s;
  if (p < 6400)      { cb = cls0; rb = reg0; ob = obj0; HW = 6400; W = 80; pl = p;        s = 8.f;  }
  else if (p < 8000) { cb = cls1; rb = reg1; ob = obj1; HW = 1600; W = 40; pl = p - 6400; s = 16.f; }
  else               { cb = cls2; rb = reg2; ob = obj2; HW = 400;  W = 20; pl = p - 8000; s = 32.f; }

  // argmax over sigmoid(cls) — first max wins (replicates jnp.argmax on sigmoid values)
  const float* cp = cb + (size_t)n * NCLS * HW + pl;
  float best = -1.0f; int bi = 0;
  for (int c = 0; c < NCLS; ++c) {
    float v = sigmoidf_(cp[(size_t)c * HW]);
    if (v > best) { best = v; bi = c; }
  }
  float osg = sigmoidf_(ob[(size_t)n * HW + pl]);
  float sc = best * osg;

  const float* rp = rb + (size_t)n * 4 * HW + pl;
  float rx = rp[0], ry = rp[(size_t)HW], rw = rp[(size_t)2 * HW], rh = rp[(size_t)3 * HW];
  int ph = pl / W, pw = pl - ph * W;
  float px = (float)pw * s, py = (float)ph * s;
  float cx = rx * s + px, cy = ry * s + py;
  float bw = expf(rw) * s, bh = expf(rh) * s;
  float x1 = cx - bw * 0.5f, y1 = cy - bh * 0.5f;
  float x2 = cx + bw * 0.5f, y2 = cy + bh * 0.5f;

  score[t] = sc;
  label[t] = bi;
  atomicAdd(&lhist[n * NCLS + bi], 1);
  float* bx = boxes + (size_t)t * 4;
  bx[0] = x1; bx[1] = y1; bx[2] = x2; bx[3] = y2;

  // per-image max over all box coords (for the class-offset trick)
  float m = fmaxf(fmaxf(x1, y1), fmaxf(x2, y2));
  unsigned long long samen = __ballot(n == __shfl(n, 0, 64));
  if (samen == ~0ull) {
    for (int o = 32; o; o >>= 1) m = fmaxf(m, __shfl_xor(m, o, 64));
    if (threadIdx.x == 0) atomicMax(&gmax[n], enc_f(m));
  } else {
    atomicMax(&gmax[n], enc_f(m));  // rare boundary waves
  }
}

// ---------------- per-image stable LSD radix sort (8 x 4-bit) -> rank permutation
// Sort ascending by U = ~enc(key) with stable ties == reference argsort(-key) stable.
// All per-(digit,thread) state in private LDS slots (no runtime-indexed reg arrays).
__global__ __launch_bounds__(256) void k_sort(
    const float* __restrict__ score, int* __restrict__ rank,
    const int* __restrict__ lhist, int* __restrict__ bstart, int* __restrict__ cursor)
{
  __shared__ uint32_t A[PTOT];        // 33.6 KB keys
  __shared__ uint16_t Pp[PTOT];       // 16.8 KB payload (orig index)
  __shared__ uint16_t hist[16 * 256]; // 8 KB   (digit-major, thread-minor)
  __shared__ uint32_t part[256];      // 1 KB
  int n = blockIdx.x, t = threadIdx.x;
  const float* sc = score + (size_t)n * PTOT;
  for (int i = t; i < PTOT; i += 256) {
    float v = sc[i];
    float key = (v >= SCORE_THR_C) ? v : -1.0f;
    A[i] = ~enc_f(key);
    Pp[i] = (uint16_t)i;
  }
  __syncthreads();
  const int base0 = t * 33;  // 256*33 = 8448 >= 8400
  for (int pass = 0; pass < 8; ++pass) {
    int sh = pass * 4;
    uint32_t k[33]; uint16_t p[33];
#pragma unroll
    for (int e = 0; e < 33; ++e) {
      int idx = base0 + e;
      if (idx < PTOT) { k[e] = A[idx]; p[e] = Pp[idx]; }
    }
    __syncthreads();                    // all loads done; A/Pp reusable
#pragma unroll
    for (int q = 0; q < 16; ++q) hist[q * 256 + t] = 0;
    __syncthreads();
#pragma unroll
    for (int e = 0; e < 33; ++e) {      // count into private slots
      int idx = base0 + e;
      if (idx < PTOT) {
        int d = (k[e] >> sh) & 15;
        hist[d * 256 + t] = (uint16_t)(hist[d * 256 + t] + 1);
      }
    }
    __syncthreads();
    // level-1: exclusive scan within 16-entry group (same digit per group)
    uint32_t s = 0;
#pragma unroll
    for (int q = 0; q < 16; ++q) {
      int f = t * 16 + q;
      uint32_t h = hist[f];
      hist[f] = (uint16_t)s;
      s += h;
    }
    part[t] = s;
    __syncthreads();
    // level-2: Hillis-Steele inclusive scan over 256 group sums
    for (int off = 1; off < 256; off <<= 1) {
      uint32_t v = (t >= off) ? part[t - off] : 0;
      __syncthreads();
      part[t] += v;
      __syncthreads();
    }
    {
      uint32_t incl = part[t];
      __syncthreads();
      part[t] = incl - s;               // exclusive group prefix
      __syncthreads();
    }
    // bases: global exclusive prefix for slot (d,t)
#pragma unroll
    for (int d = 0; d < 16; ++d) {
      int f = d * 256 + t;
      hist[f] = (uint16_t)(hist[f] + part[f >> 4]);
    }
    __syncthreads();
    // stable scatter (slots double as running cursors)
#pragma unroll
    for (int e = 0; e < 33; ++e) {
      int idx = base0 + e;
      if (idx < PTOT) {
        int d = (k[e] >> sh) & 15;
        int f = d * 256 + t;
        uint32_t pos = hist[f];
        hist[f] = (uint16_t)(pos + 1);
        A[pos] = k[e];
        Pp[pos] = p[e];
      }
    }
    __syncthreads();
  }
  for (int pos = t; pos < PTOT; pos += 256)
    rank[(size_t)n * PTOT + Pp[pos]] = pos;
  // label-bucket exclusive scan (fold of old k_bscan)
  if (t == 0) {
    int acc = 0;
    for (int L = 0; L < NCLS; ++L) { bstart[n * (NCLS + 1) + L] = acc; acc += lhist[n * NCLS + L]; }
    bstart[n * (NCLS + 1) + NCLS] = acc;
  }
  __syncthreads();
  if (t < NCLS) cursor[n * NCLS + t] = bstart[n * (NCLS + 1) + t];
}

// ---------------- scatter into sorted order + shifted boxes/areas + nvalid + bucket fill
__global__ __launch_bounds__(256) void k_scatter(
    const float* __restrict__ score, const int* __restrict__ label, const float* __restrict__ boxes,
    const unsigned* __restrict__ gmax, const int* __restrict__ rank, int* __restrict__ nvalid,
    float* __restrict__ s_score, int* __restrict__ s_label,
    float* __restrict__ s_box, float* __restrict__ s_sbox, float* __restrict__ s_area,
    int* __restrict__ cursor, int* __restrict__ bidx)
{
  int n = blockIdx.y;
  int i = blockIdx.x * 256 + threadIdx.x;
  if (i >= PTOT) return;
  const float* sc = score + (size_t)n * PTOT;
  float v = sc[i];
  bool valid = (v >= SCORE_THR_C);
  unsigned long long bal = __ballot(valid);
  if ((threadIdx.x & 63) == 0) atomicAdd(&nvalid[n], (int)__popcll(bal));

  int r = rank[(size_t)n * PTOT + i];  // stable permutation
  float gm = dec_f(gmax[n]);
  int li = label[(size_t)n * PTOT + i];
  const float* bp = boxes + ((size_t)n * PTOT + i) * 4;
  float b0 = bp[0], b1 = bp[1], b2 = bp[2], b3 = bp[3];
  float off = (float)li * (gm + 1.0f);
  float q0 = b0 + off, q1 = b1 + off, q2 = b2 + off, q3 = b3 + off;
  float area = (q2 - q0) * (q3 - q1);   // area from SHIFTED coords (matches reference)

  size_t d = (size_t)n * PTOT + (size_t)r;
  s_score[d] = v;
  s_label[d] = li;
  float* sb = s_box + d * 4;  sb[0] = b0; sb[1] = b1; sb[2] = b2; sb[3] = b3;
  float* sq = s_sbox + d * 4; sq[0] = q0; sq[1] = q1; sq[2] = q2; sq[3] = q3;
  s_area[d] = area;
  // bucket fill (fold of old k_bfill) — within-bucket order irrelevant for k_pairs
  int pos = atomicAdd(&cursor[n * NCLS + li], 1);
  bidx[(size_t)n * PTOT + pos] = r;
}

// ---------------- sparse pair IoU: same-label + up-to-DMAX-adjacent-label pairs
// (class-offset slabs make farther labels provably non-overlapping)
__global__ __launch_bounds__(256) void k_pairs(
    const float* __restrict__ s_sbox, const float* __restrict__ s_area,
    const int* __restrict__ bstart, const int* __restrict__ bidx,
    uint64_t* __restrict__ mask, uint64_t* __restrict__ diag, uint64_t* __restrict__ flags)
{
  int n = blockIdx.z, L = blockIdx.x, d = blockIdx.y;
  int L2 = L + d;
  if (L2 >= NCLS) return;
  const int* bs = bstart + n * (NCLS + 1);
  int a0 = bs[L], a1 = bs[L + 1];
  int b0 = bs[L2], b1 = bs[L2 + 1];
  int na = a1 - a0, nb = b1 - b0;
  if (na == 0 || nb == 0) return;
  const int* ba = bidx + (size_t)n * PTOT + a0;
  const int* bb = bidx + (size_t)n * PTOT + b0;
  const float4* SB = (const float4*)(s_sbox + (size_t)n * PTOT * 4);
  const float* SA = s_area + (size_t)n * PTOT;
  int tot = na * nb;
  for (int t = threadIdx.x; t < tot; t += 256) {
    int u = t / nb, v = t - u * nb;
    if (d == 0 && u >= v) continue;          // unordered within-bucket pairs
    int p = ba[u], q = bb[v];
    float4 A = SB[p], B = SB[q];
    float ww = fminf(A.z, B.z) - fmaxf(A.x, B.x);
    float hh = fminf(A.w, B.w) - fmaxf(A.y, B.y);
    if (ww <= 0.0f || hh <= 0.0f) continue;  // inter=0 -> iou=0 -> no bit (exact)
    float inter = ww * hh;                   // == clip(ww)*clip(hh) here
    float aa = SA[p], ab = SA[q];
    float uni = fmaxf(aa + ab - inter, 1e-12f);
    if (inter / uni > NMS_THR_C) {           // identical arithmetic to reference
      int i = min(p, q), j = max(p, q);
      int iw = i >> 6, jw = j >> 6;
      if (iw == jw) {
        atomicOr((unsigned long long*)&diag[(size_t)n * DSTR + i], 1ull << (j & 63));
      } else {
        atomicOr((unsigned long long*)&mask[((size_t)n * PTOT + i) * NW + jw], 1ull << (j & 63));
        atomicOr((unsigned long long*)&flags[(size_t)n * NW + iw], 1ull << (i & 63));
      }
    }
  }
}

// ---------------- greedy suppression scan: 1 wave per image, sparse chunk walk
__global__ __launch_bounds__(64) void k_scan(
    const uint64_t* __restrict__ mask,
    const uint64_t* __restrict__ diag,
    const uint64_t* __restrict__ flags,
    const int* __restrict__ nvalid,
    uint64_t* __restrict__ keepw)
{
  int n = blockIdx.x, l = threadIdx.x;
  int nv = nvalid[n];

  // removed-mask init: sorted order puts invalid boxes last -> removed = bits >= nv
  // lane l owns words l, 64+l, (l<4: 128+l)
  auto initw = [&](int w) -> uint64_t {
    int base = w * 64;
    if (nv <= base) return ~0ull;
    if (nv >= base + 64) return 0ull;
    return (~0ull) << (nv - base);
  };
  uint64_t r0 = initw(l), r1 = initw(64 + l), r2 = (l < 4) ? initw(128 + l) : 0ull;

  const uint64_t* fl = flags + (size_t)n * NW;
  uint64_t f0 = fl[l], f1 = fl[64 + l], f2 = (l < 4) ? fl[128 + l] : 0ull;
  const uint64_t* dg = diag + (size_t)n * DSTR;
  const uint64_t* mrow = mask + (size_t)n * PTOT * NW;

  // diag word prefetch, depth 2 (lane l holds row c*64+l's in-chunk word)
  uint64_t dcur = dg[l];
  uint64_t dnxt = dg[64 + l];

  for (int c = 0; c < NW; ++c) {
    uint64_t d = dcur;
    dcur = dnxt;
    if (c + 2 < NW) dnxt = dg[(size_t)(c + 2) * 64 + l];

    int ol = c & 63;  // owner lane of word c in its slot
    uint64_t srcw = (c < 64) ? r0 : ((c < 128) ? r1 : r2);
    uint64_t R = __shfl(srcw, ol, 64);          // removed word for this chunk (uniform)
    uint64_t fsrc = (c < 64) ? f0 : ((c < 128) ? f1 : f2);
    uint64_t F = __shfl(fsrc, ol, 64);          // rows with off-diag suppression bits

    // in-chunk greedy resolve: only rows with nonzero diag words matter
    uint64_t nz = __ballot(d != 0ull);
    uint64_t pending = nz & ~R;
    while (pending) {
      int b = __builtin_ctzll(pending);
      uint64_t row = __shfl(d, b, 64);          // bits only for j>b within chunk
      R |= row;
      pending &= ~R;
      pending &= pending - 1;                    // clear bit b (still lowest)
    }
    if (l == ol) { if (c < 64) r0 = R; else if (c < 128) r1 = R; else r2 = R; }

    // OR full rows of kept+flagged boxes into future removed words (word > c only);
    // mask is zero-initialized, so unwritten words contribute nothing
    uint64_t kf = F & ~R;
    uint64_t m0 = (l > c) ? ~0ull : 0ull;
    uint64_t m1 = (64 + l > c) ? ~0ull : 0ull;
    uint64_t m2 = (128 + l > c) ? ~0ull : 0ull;
    while (kf) {
      int b1 = __builtin_ctzll(kf); kf &= kf - 1;
      const uint64_t* rp1 = mrow + (size_t)(c * 64 + b1) * NW;
      uint64_t a0 = rp1[l], a1 = rp1[64 + l], a2 = (l < 4) ? rp1[128 + l] : 0ull;
      if (kf) {  // 2-way unroll to overlap load latency
        int b2 = __builtin_ctzll(kf); kf &= kf - 1;
        const uint64_t* rp2 = mrow + (size_t)(c * 64 + b2) * NW;
        uint64_t c0 = rp2[l], c1 = rp2[64 + l], c2 = (l < 4) ? rp2[128 + l] : 0ull;
        a0 |= c0; a1 |= c1; a2 |= c2;
      }
      r0 |= a0 & m0;
      r1 |= a1 & m1;
      if (l < 4) r2 |= a2 & m2;
    }
  }

  keepw[(size_t)n * NW + l] = ~r0;
  keepw[(size_t)n * NW + 64 + l] = ~r1;
  if (l < 4) keepw[(size_t)n * NW + 128 + l] = ~r2;
}

// ---------------- finalize outputs
__global__ __launch_bounds__(256) void k_final(
    const float* __restrict__ s_score, const int* __restrict__ s_label,
    const float* __restrict__ s_box, const uint64_t* __restrict__ keepw,
    float* __restrict__ out)
{
  int t = blockIdx.x * 256 + threadIdx.x;
  if (t >= NIMG * PTOT) return;
  int n = t / PTOT, p = t - n * PTOT;
  uint64_t w = keepw[(size_t)n * NW + (p >> 6)];
  float k = (float)((w >> (p & 63)) & 1ull);
  float* dets = out;
  float* lab  = out + (size_t)NIMG * PTOT * 5;
  float* kp   = out + (size_t)NIMG * PTOT * 6;
  const float* bp = s_box + (size_t)t * 4;
  float* dp = dets + (size_t)t * 5;
  dp[0] = bp[0] * k; dp[1] = bp[1] * k; dp[2] = bp[2] * k; dp[3] = bp[3] * k;
  dp[4] = s_score[t] * k;
  lab[t] = (float)s_label[t];
  kp[t]  = k;
}

extern "C" void kernel_launch(void* const* d_in, const int* in_sizes, int n_in,
                              void* d_out, int out_size, void* d_ws, size_t ws_size,
                              hipStream_t stream)
{
  const float* cls0 = (const float*)d_in[0];
  const float* cls1 = (const float*)d_in[1];
  const float* cls2 = (const float*)d_in[2];
  const float* reg0 = (const float*)d_in[3];
  const float* reg1 = (const float*)d_in[4];
  const float* reg2 = (const float*)d_in[5];
  const float* obj0 = (const float*)d_in[6];
  const float* obj1 = (const float*)d_in[7];
  const float* obj2 = (const float*)d_in[8];

  char* w = (char*)d_ws;
  uint64_t* mask = (uint64_t*)w;  w += (size_t)NIMG * PTOT * NW * 8;  // 35,481,600 B (zeroed in k_init)
  uint64_t* keepw = (uint64_t*)w; w += (size_t)NIMG * NW * 8;
  float* score = (float*)w;       w += (size_t)NIMG * PTOT * 4;
  int*   label = (int*)w;         w += (size_t)NIMG * PTOT * 4;
  float* boxes = (float*)w;       w += (size_t)NIMG * PTOT * 16;
  float* ss = (float*)w;          w += (size_t)NIMG * PTOT * 4;
  int*   sl = (int*)w;            w += (size_t)NIMG * PTOT * 4;
  float* sb = (float*)w;          w += (size_t)NIMG * PTOT * 16;
  float* sq = (float*)w;          w += (size_t)NIMG * PTOT * 16;
  float* sa = (float*)w;          w += (size_t)NIMG * PTOT * 4;
  unsigned* gmax = (unsigned*)w;  w += 256;                            // 4 used, pad for align
  uint64_t* diag = (uint64_t*)w;  w += (size_t)NIMG * DSTR * 8;        // 270,336 B
  uint64_t* flags = (uint64_t*)w; w += (size_t)NIMG * NW * 8;          // 4,224 B
  int* nvalid = (int*)w;          w += 256;
  int* rank = (int*)w;            w += (size_t)NIMG * PTOT * 4;
  int* lhist = (int*)w;           w += (size_t)NIMG * NCLS * 4;        // 1,280 B
  int* bstart = (int*)w;          w += (size_t)NIMG * (NCLS + 1) * 4;  // 1,296 B
  int* cursor = (int*)w;          w += (size_t)NIMG * NCLS * 4;
  int* bidx = (int*)w;            w += (size_t)NIMG * PTOT * 4;

  k_init<<<dim3(512), dim3(256), 0, stream>>>(gmax, flags, nvalid, diag, lhist, (uint4*)mask);
  k_decode<<<dim3((NIMG * PTOT) / 64), dim3(64), 0, stream>>>(
      cls0, cls1, cls2, reg0, reg1, reg2, obj0, obj1, obj2,
      score, label, boxes, gmax, lhist);
  k_sort<<<dim3(NIMG), dim3(256), 0, stream>>>(score, rank, lhist, bstart, cursor);
  k_scatter<<<dim3((PTOT + 255) / 256, NIMG), dim3(256), 0, stream>>>(
      score, label, boxes, gmax, rank, nvalid, ss, sl, sb, sq, sa, cursor, bidx);
  k_pairs<<<dim3(NCLS, DMAX + 1, NIMG), dim3(256), 0, stream>>>(
      sq, sa, bstart, bidx, mask, diag, flags);
  k_scan<<<dim3(NIMG), dim3(64), 0, stream>>>(mask, diag, flags, nvalid, keepw);
  k_final<<<dim3((NIMG * PTOT + 255) / 256), dim3(256), 0, stream>>>(
      ss, sl, sb, keepw, (float*)d_out);
}

// Round 8
// 253.046 us; speedup vs baseline: 6.0720x; 1.0485x over previous
//
#include <hip/hip_runtime.h>
#include <stdint.h>

#define NIMG 4
#define PTOT 8400
#define NCLS 80
#define NW   132            // 64-bit words per mask row (ceil(8400/64))
#define DSTR (NW * 64)      // 8448: padded rows per image in diag array
#define DMAX 3              // max label distance with possible slab overlap (provably safe)
#define NPAD 8448           // padded sort size (= 256 threads * 33)
#define NMS_THR_C 0.65f
#define SCORE_THR_C 0.01f

static __device__ __forceinline__ float sigmoidf_(float x) {
  return 1.0f / (1.0f + expf(-x));
}
// order-preserving float->uint encoding for atomicMax
static __device__ __forceinline__ unsigned enc_f(float f) {
  unsigned u = __float_as_uint(f);
  return (u >> 31) ? ~u : (u | 0x80000000u);
}
static __device__ __forceinline__ float dec_f(unsigned e) {
  return (e >> 31) ? __uint_as_float(e ^ 0x80000000u) : __uint_as_float(~e);
}

__global__ void k_init(unsigned* gmax, uint64_t* flags, int* nvalid, uint64_t* diag,
                       int* lhist, uint4* mask4) {
  int t = blockIdx.x * 256 + threadIdx.x;
  int NT = gridDim.x * 256;
  // mask zero-fill: 35,481,600 B = 2,217,600 uint4 (atomicOr targets MUST start at 0:
  // harness poisons ws with 0xAA before every launch)
  const int M4 = NIMG * PTOT * NW / 2;
  for (int k = t; k < M4; k += NT) mask4[k] = make_uint4(0, 0, 0, 0);
  for (int k = t; k < NIMG * DSTR; k += NT) diag[k] = 0ull;
  for (int k = t; k < NIMG * NW; k += NT) flags[k] = 0ull;
  for (int k = t; k < NIMG * NCLS; k += NT) lhist[k] = 0;
  if (t < NIMG) { gmax[t] = 0u; nvalid[t] = 0; }
}

// ---------------- decode: sigmoid + argmax + box decode + coord max + label hist
__global__ __launch_bounds__(64) void k_decode(
    const float* __restrict__ cls0, const float* __restrict__ cls1, const float* __restrict__ cls2,
    const float* __restrict__ reg0, const float* __restrict__ reg1, const float* __restrict__ reg2,
    const float* __restrict__ obj0, const float* __restrict__ obj1, const float* __restrict__ obj2,
    float* __restrict__ score, int* __restrict__ label, float* __restrict__ boxes,
    unsigned* __restrict__ gmax, int* __restrict__ lhist)
{
  int t = blockIdx.x * 64 + threadIdx.x;   // grid = 525*64 == 33600 exactly
  int n = t / PTOT;
  int p = t - n * PTOT;
  const float* cb; const float* rb; const float* ob;
  int HW, W, pl; float s;
  if (p < 6400)      { cb = cls0; rb = reg0; ob = obj0; HW = 6400; W = 80; pl = p;        s = 8.f;  }
  else if (p < 8000) { cb = cls1; rb = reg1; ob = obj1; HW = 1600; W = 40; pl = p - 6400; s = 16.f; }
  else               { cb = cls2; rb = reg2; ob = obj2; HW = 400;  W = 20; pl = p - 8000; s = 32.f; }

  // argmax over sigmoid(cls) — first max wins (replicates jnp.argmax on sigmoid values)
  const float* cp = cb + (size_t)n * NCLS * HW + pl;
  float best = -1.0f; int bi = 0;
  for (int c = 0; c < NCLS; ++c) {
    float v = sigmoidf_(cp[(size_t)c * HW]);
    if (v > best) { best = v; bi = c; }
  }
  float osg = sigmoidf_(ob[(size_t)n * HW + pl]);
  float sc = best * osg;

  const float* rp = rb + (size_t)n * 4 * HW + pl;
  float rx = rp[0], ry = rp[(size_t)HW], rw = rp[(size_t)2 * HW], rh = rp[(size_t)3 * HW];
  int ph = pl / W, pw = pl - ph * W;
  float px = (float)pw * s, py = (float)ph * s;
  float cx = rx * s + px, cy = ry * s + py;
  float bw = expf(rw) * s, bh = expf(rh) * s;
  float x1 = cx - bw * 0.5f, y1 = cy - bh * 0.5f;
  float x2 = cx + bw * 0.5f, y2 = cy + bh * 0.5f;

  score[t] = sc;
  label[t] = bi;
  atomicAdd(&lhist[n * NCLS + bi], 1);
  float* bx = boxes + (size_t)t * 4;
  bx[0] = x1; bx[1] = y1; bx[2] = x2; bx[3] = y2;

  // per-image max over all box coords (for the class-offset trick)
  float m = fmaxf(fmaxf(x1, y1), fmaxf(x2, y2));
  unsigned long long samen = __ballot(n == __shfl(n, 0, 64));
  if (samen == ~0ull) {
    for (int o = 32; o; o >>= 1) m = fmaxf(m, __shfl_xor(m, o, 64));
    if (threadIdx.x == 0) atomicMax(&gmax[n], enc_f(m));
  } else {
    atomicMax(&gmax[n], enc_f(m));  // rare boundary waves
  }
}

// ---------------- per-image stable LSD radix sort (8 x 4-bit) -> rank permutation
// Same permutation as R7's verified sort (digit-major, thread-major, within-thread
// order), but all serial LDS rmw chains replaced by packed-register counters and
// the Hillis-Steele barrier cascade replaced by a shfl wave scan.
__global__ __launch_bounds__(256) void k_sort(
    const float* __restrict__ score, int* __restrict__ rank,
    const int* __restrict__ lhist, int* __restrict__ bstart, int* __restrict__ cursor)
{
  __shared__ uint32_t A[NPAD];        // 33.8 KB keys
  __shared__ uint16_t Pp[NPAD];       // 16.9 KB payload (orig index)
  __shared__ uint16_t hist[16 * 256]; // 8 KB (slot f = d*256+t)
  __shared__ uint32_t part[256];      // 1 KB group exclusive prefixes
  __shared__ uint32_t wsum[4];
  int n = blockIdx.x, t = threadIdx.x;
  const float* sc = score + (size_t)n * PTOT;
  for (int i = t; i < PTOT; i += 256) {
    float v = sc[i];
    float key = (v >= SCORE_THR_C) ? v : -1.0f;
    A[i] = ~enc_f(key);               // real keys <= 0xBF800000
    Pp[i] = (uint16_t)i;
  }
  for (int i = PTOT + t; i < NPAD; i += 256) {
    A[i] = 0xFFFFFFFFu;               // strictly greater than any real key -> sorts last
    Pp[i] = (uint16_t)i;
  }
  __syncthreads();
  const int base0 = t * 33;           // 256*33 == NPAD
  for (int pass = 0; pass < 8; ++pass) {
    const int sh = pass * 4;
    uint32_t k[33]; uint16_t p[33];
#pragma unroll
    for (int e = 0; e < 33; ++e) { k[e] = A[base0 + e]; p[e] = Pp[base0 + e]; }
    // count phase: 16 digit counters packed 8-bit into two u64 (no LDS rmw)
    uint64_t c0 = 0, c1 = 0;
#pragma unroll
    for (int e = 0; e < 33; ++e) {
      uint32_t d = (k[e] >> sh) & 15u;
      uint64_t inc = 1ull << ((d & 7u) << 3);
      if (d < 8) c0 += inc; else c1 += inc;
    }
#pragma unroll
    for (int d = 0; d < 16; ++d) {
      uint32_t cnt = (uint32_t)(((d < 8) ? (c0 >> (d * 8)) : (c1 >> ((d - 8) * 8))) & 0xFFull);
      hist[d * 256 + t] = (uint16_t)cnt;
    }
    __syncthreads();
    // level-1: exclusive scan within 16-slot group f = t*16..t*16+15 (independent LDS)
    uint32_t s = 0;
#pragma unroll
    for (int q = 0; q < 16; ++q) {
      int f = t * 16 + q;
      uint32_t h = hist[f];
      hist[f] = (uint16_t)s;
      s += h;
    }
    // wave-level inclusive shfl scan of group totals over t
    uint32_t v = s;
#pragma unroll
    for (int off = 1; off < 64; off <<= 1) {
      uint32_t u = __shfl_up(v, off, 64);
      if ((t & 63) >= off) v += u;
    }
    if ((t & 63) == 63) wsum[t >> 6] = v;
    __syncthreads();
    uint32_t wpre = 0;
#pragma unroll
    for (int wv = 0; wv < 4; ++wv) wpre += (wv < (t >> 6)) ? wsum[wv] : 0;
    part[t] = v - s + wpre;           // exclusive prefix of group t
    __syncthreads();
    // scatter: pos = hist[f] + part[f>>4] + within-thread running count (packed regs)
    uint64_t cc0 = 0, cc1 = 0;
#pragma unroll
    for (int e = 0; e < 33; ++e) {
      uint32_t d = (k[e] >> sh) & 15u;
      int f = d * 256 + t;
      uint32_t within = (uint32_t)(((d < 8) ? (cc0 >> ((d & 7u) << 3))
                                            : (cc1 >> ((d & 7u) << 3))) & 0xFFull);
      uint32_t pos = (uint32_t)hist[f] + part[f >> 4] + within;
      A[pos] = k[e];
      Pp[pos] = p[e];
      uint64_t inc = 1ull << ((d & 7u) << 3);
      if (d < 8) cc0 += inc; else cc1 += inc;
    }
    __syncthreads();
  }
  for (int pos = t; pos < PTOT; pos += 256)   // pads occupy pos >= PTOT only
    rank[(size_t)n * PTOT + Pp[pos]] = pos;
  // label-bucket exclusive scan (fold of old k_bscan)
  if (t == 0) {
    int acc = 0;
    for (int L = 0; L < NCLS; ++L) { bstart[n * (NCLS + 1) + L] = acc; acc += lhist[n * NCLS + L]; }
    bstart[n * (NCLS + 1) + NCLS] = acc;
  }
  __syncthreads();
  if (t < NCLS) cursor[n * NCLS + t] = bstart[n * (NCLS + 1) + t];
}

// ---------------- scatter into sorted order + shifted boxes/areas + nvalid + bucket fill
__global__ __launch_bounds__(256) void k_scatter(
    const float* __restrict__ score, const int* __restrict__ label, const float* __restrict__ boxes,
    const unsigned* __restrict__ gmax, const int* __restrict__ rank, int* __restrict__ nvalid,
    float* __restrict__ s_score, int* __restrict__ s_label,
    float* __restrict__ s_box, float* __restrict__ s_sbox, float* __restrict__ s_area,
    int* __restrict__ cursor, int* __restrict__ bidx)
{
  int n = blockIdx.y;
  int i = blockIdx.x * 256 + threadIdx.x;
  if (i >= PTOT) return;
  const float* sc = score + (size_t)n * PTOT;
  float v = sc[i];
  bool valid = (v >= SCORE_THR_C);
  unsigned long long bal = __ballot(valid);
  if ((threadIdx.x & 63) == 0) atomicAdd(&nvalid[n], (int)__popcll(bal));

  int r = rank[(size_t)n * PTOT + i];  // stable permutation
  float gm = dec_f(gmax[n]);
  int li = label[(size_t)n * PTOT + i];
  const float* bp = boxes + ((size_t)n * PTOT + i) * 4;
  float b0 = bp[0], b1 = bp[1], b2 = bp[2], b3 = bp[3];
  float off = (float)li * (gm + 1.0f);
  float q0 = b0 + off, q1 = b1 + off, q2 = b2 + off, q3 = b3 + off;
  float area = (q2 - q0) * (q3 - q1);   // area from SHIFTED coords (matches reference)

  size_t d = (size_t)n * PTOT + (size_t)r;
  s_score[d] = v;
  s_label[d] = li;
  float* sb = s_box + d * 4;  sb[0] = b0; sb[1] = b1; sb[2] = b2; sb[3] = b3;
  float* sq = s_sbox + d * 4; sq[0] = q0; sq[1] = q1; sq[2] = q2; sq[3] = q3;
  s_area[d] = area;
  // bucket fill (fold of old k_bfill) — within-bucket order irrelevant for k_pairs
  int pos = atomicAdd(&cursor[n * NCLS + li], 1);
  bidx[(size_t)n * PTOT + pos] = r;
}

// ---------------- sparse pair IoU: same-label + up-to-DMAX-adjacent-label pairs
// (class-offset slabs make farther labels provably non-overlapping)
__global__ __launch_bounds__(256) void k_pairs(
    const float* __restrict__ s_sbox, const float* __restrict__ s_area,
    const int* __restrict__ bstart, const int* __restrict__ bidx,
    uint64_t* __restrict__ mask, uint64_t* __restrict__ diag, uint64_t* __restrict__ flags)
{
  int n = blockIdx.z, L = blockIdx.x, d = blockIdx.y;
  int L2 = L + d;
  if (L2 >= NCLS) return;
  const int* bs = bstart + n * (NCLS + 1);
  int a0 = bs[L], a1 = bs[L + 1];
  int b0 = bs[L2], b1 = bs[L2 + 1];
  int na = a1 - a0, nb = b1 - b0;
  if (na == 0 || nb == 0) return;
  const int* ba = bidx + (size_t)n * PTOT + a0;
  const int* bb = bidx + (size_t)n * PTOT + b0;
  const float4* SB = (const float4*)(s_sbox + (size_t)n * PTOT * 4);
  const float* SA = s_area + (size_t)n * PTOT;
  int tot = na * nb;
  for (int t = threadIdx.x; t < tot; t += 256) {
    int u = t / nb, v = t - u * nb;
    if (d == 0 && u >= v) continue;          // unordered within-bucket pairs
    int p = ba[u], q = bb[v];
    float4 A = SB[p], B = SB[q];
    float ww = fminf(A.z, B.z) - fmaxf(A.x, B.x);
    float hh = fminf(A.w, B.w) - fmaxf(A.y, B.y);
    if (ww <= 0.0f || hh <= 0.0f) continue;  // inter=0 -> iou=0 -> no bit (exact)
    float inter = ww * hh;                   // == clip(ww)*clip(hh) here
    float aa = SA[p], ab = SA[q];
    float uni = fmaxf(aa + ab - inter, 1e-12f);
    if (inter / uni > NMS_THR_C) {           // identical arithmetic to reference
      int i = min(p, q), j = max(p, q);
      int iw = i >> 6, jw = j >> 6;
      if (iw == jw) {
        atomicOr((unsigned long long*)&diag[(size_t)n * DSTR + i], 1ull << (j & 63));
      } else {
        atomicOr((unsigned long long*)&mask[((size_t)n * PTOT + i) * NW + jw], 1ull << (j & 63));
        atomicOr((unsigned long long*)&flags[(size_t)n * NW + iw], 1ull << (i & 63));
      }
    }
  }
}

// ---------------- greedy suppression scan: 1 wave per image, sparse chunk walk
__global__ __launch_bounds__(64) void k_scan(
    const uint64_t* __restrict__ mask,
    const uint64_t* __restrict__ diag,
    const uint64_t* __restrict__ flags,
    const int* __restrict__ nvalid,
    uint64_t* __restrict__ keepw)
{
  int n = blockIdx.x, l = threadIdx.x;
  int nv = nvalid[n];

  // removed-mask init: sorted order puts invalid boxes last -> removed = bits >= nv
  // lane l owns words l, 64+l, (l<4: 128+l)
  auto initw = [&](int w) -> uint64_t {
    int base = w * 64;
    if (nv <= base) return ~0ull;
    if (nv >= base + 64) return 0ull;
    return (~0ull) << (nv - base);
  };
  uint64_t r0 = initw(l), r1 = initw(64 + l), r2 = (l < 4) ? initw(128 + l) : 0ull;

  const uint64_t* fl = flags + (size_t)n * NW;
  uint64_t f0 = fl[l], f1 = fl[64 + l], f2 = (l < 4) ? fl[128 + l] : 0ull;
  const uint64_t* dg = diag + (size_t)n * DSTR;
  const uint64_t* mrow = mask + (size_t)n * PTOT * NW;

  // diag word prefetch, depth 2 (lane l holds row c*64+l's in-chunk word)
  uint64_t dcur = dg[l];
  uint64_t dnxt = dg[64 + l];

  for (int c = 0; c < NW; ++c) {
    uint64_t d = dcur;
    dcur = dnxt;
    if (c + 2 < NW) dnxt = dg[(size_t)(c + 2) * 64 + l];

    int ol = c & 63;  // owner lane of word c in its slot
    uint64_t srcw = (c < 64) ? r0 : ((c < 128) ? r1 : r2);
    uint64_t R = __shfl(srcw, ol, 64);          // removed word for this chunk (uniform)
    uint64_t fsrc = (c < 64) ? f0 : ((c < 128) ? f1 : f2);
    uint64_t F = __shfl(fsrc, ol, 64);          // rows with off-diag suppression bits

    // in-chunk greedy resolve: only rows with nonzero diag words matter
    uint64_t nz = __ballot(d != 0ull);
    uint64_t pending = nz & ~R;
    while (pending) {
      int b = __builtin_ctzll(pending);
      uint64_t row = __shfl(d, b, 64);          // bits only for j>b within chunk
      R |= row;
      pending &= ~R;
      pending &= pending - 1;                    // clear bit b (still lowest)
    }
    if (l == ol) { if (c < 64) r0 = R; else if (c < 128) r1 = R; else r2 = R; }

    // OR full rows of kept+flagged boxes into future removed words (word > c only);
    // mask is zero-initialized, so unwritten words contribute nothing
    uint64_t kf = F & ~R;
    uint64_t m0 = (l > c) ? ~0ull : 0ull;
    uint64_t m1 = (64 + l > c) ? ~0ull : 0ull;
    uint64_t m2 = (128 + l > c) ? ~0ull : 0ull;
    while (kf) {
      int b1 = __builtin_ctzll(kf); kf &= kf - 1;
      const uint64_t* rp1 = mrow + (size_t)(c * 64 + b1) * NW;
      uint64_t a0 = rp1[l], a1 = rp1[64 + l], a2 = (l < 4) ? rp1[128 + l] : 0ull;
      if (kf) {  // 2-way unroll to overlap load latency
        int b2 = __builtin_ctzll(kf); kf &= kf - 1;
        const uint64_t* rp2 = mrow + (size_t)(c * 64 + b2) * NW;
        uint64_t c0 = rp2[l], c1 = rp2[64 + l], c2 = (l < 4) ? rp2[128 + l] : 0ull;
        a0 |= c0; a1 |= c1; a2 |= c2;
      }
      r0 |= a0 & m0;
      r1 |= a1 & m1;
      if (l < 4) r2 |= a2 & m2;
    }
  }

  keepw[(size_t)n * NW + l] = ~r0;
  keepw[(size_t)n * NW + 64 + l] = ~r1;
  if (l < 4) keepw[(size_t)n * NW + 128 + l] = ~r2;
}

// ---------------- finalize outputs
__global__ __launch_bounds__(256) void k_final(
    const float* __restrict__ s_score, const int* __restrict__ s_label,
    const float* __restrict__ s_box, const uint64_t* __restrict__ keepw,
    float* __restrict__ out)
{
  int t = blockIdx.x * 256 + threadIdx.x;
  if (t >= NIMG * PTOT) return;
  int n = t / PTOT, p = t - n * PTOT;
  uint64_t w = keepw[(size_t)n * NW + (p >> 6)];
  float k = (float)((w >> (p & 63)) & 1ull);
  float* dets = out;
  float* lab  = out + (size_t)NIMG * PTOT * 5;
  float* kp   = out + (size_t)NIMG * PTOT * 6;
  const float* bp = s_box + (size_t)t * 4;
  float* dp = dets + (size_t)t * 5;
  dp[0] = bp[0] * k; dp[1] = bp[1] * k; dp[2] = bp[2] * k; dp[3] = bp[3] * k;
  dp[4] = s_score[t] * k;
  lab[t] = (float)s_label[t];
  kp[t]  = k;
}

extern "C" void kernel_launch(void* const* d_in, const int* in_sizes, int n_in,
                              void* d_out, int out_size, void* d_ws, size_t ws_size,
                              hipStream_t stream)
{
  const float* cls0 = (const float*)d_in[0];
  const float* cls1 = (const float*)d_in[1];
  const float* cls2 = (const float*)d_in[2];
  const float* reg0 = (const float*)d_in[3];
  const float* reg1 = (const float*)d_in[4];
  const float* reg2 = (const float*)d_in[5];
  const float* obj0 = (const float*)d_in[6];
  const float* obj1 = (const float*)d_in[7];
  const float* obj2 = (const float*)d_in[8];

  char* w = (char*)d_ws;
  uint64_t* mask = (uint64_t*)w;  w += (size_t)NIMG * PTOT * NW * 8;  // 35,481,600 B (zeroed in k_init)
  uint64_t* keepw = (uint64_t*)w; w += (size_t)NIMG * NW * 8;
  float* score = (float*)w;       w += (size_t)NIMG * PTOT * 4;
  int*   label = (int*)w;         w += (size_t)NIMG * PTOT * 4;
  float* boxes = (float*)w;       w += (size_t)NIMG * PTOT * 16;
  float* ss = (float*)w;          w += (size_t)NIMG * PTOT * 4;
  int*   sl = (int*)w;            w += (size_t)NIMG * PTOT * 4;
  float* sb = (float*)w;          w += (size_t)NIMG * PTOT * 16;
  float* sq = (float*)w;          w += (size_t)NIMG * PTOT * 16;
  float* sa = (float*)w;          w += (size_t)NIMG * PTOT * 4;
  unsigned* gmax = (unsigned*)w;  w += 256;                            // 4 used, pad for align
  uint64_t* diag = (uint64_t*)w;  w += (size_t)NIMG * DSTR * 8;        // 270,336 B
  uint64_t* flags = (uint64_t*)w; w += (size_t)NIMG * NW * 8;          // 4,224 B
  int* nvalid = (int*)w;          w += 256;
  int* rank = (int*)w;            w += (size_t)NIMG * PTOT * 4;
  int* lhist = (int*)w;           w += (size_t)NIMG * NCLS * 4;        // 1,280 B
  int* bstart = (int*)w;          w += (size_t)NIMG * (NCLS + 1) * 4;  // 1,296 B
  int* cursor = (int*)w;          w += (size_t)NIMG * NCLS * 4;
  int* bidx = (int*)w;            w += (size_t)NIMG * PTOT * 4;

  k_init<<<dim3(512), dim3(256), 0, stream>>>(gmax, flags, nvalid, diag, lhist, (uint4*)mask);
  k_decode<<<dim3((NIMG * PTOT) / 64), dim3(64), 0, stream>>>(
      cls0, cls1, cls2, reg0, reg1, reg2, obj0, obj1, obj2,
      score, label, boxes, gmax, lhist);
  k_sort<<<dim3(NIMG), dim3(256), 0, stream>>>(score, rank, lhist, bstart, cursor);
  k_scatter<<<dim3((PTOT + 255) / 256, NIMG), dim3(256), 0, stream>>>(
      score, label, boxes, gmax, rank, nvalid, ss, sl, sb, sq, sa, cursor, bidx);
  k_pairs<<<dim3(NCLS, DMAX + 1, NIMG), dim3(256), 0, stream>>>(
      sq, sa, bstart, bidx, mask, diag, flags);
  k_scan<<<dim3(NIMG), dim3(64), 0, stream>>>(mask, diag, flags, nvalid, keepw);
  k_final<<<dim3((NIMG * PTOT + 255) / 256), dim3(256), 0, stream>>>(
      ss, sl, sb, keepw, (float*)d_out);
}

// Round 9
// 209.194 us; speedup vs baseline: 7.3448x; 1.2096x over previous
//
#include <hip/hip_runtime.h>
#include <stdint.h>

#define NIMG 4
#define PTOT 8400
#define NCLS 80
#define NW   132            // 64-bit words per removed-bitmask row (ceil(8400/64))
#define DMAX 3              // max label distance with possible slab overlap (provably safe)
#define NPAD 8448           // padded sort size (= 256 threads * 33)
#define ECAP 65536          // edge buffer capacity per image (expected ~150)
#define ERCAP 1024          // register-resident edge fast path (16 slots x 64 lanes)
#define NMS_THR_C 0.65f
#define SCORE_THR_C 0.01f

static __device__ __forceinline__ float sigmoidf_(float x) {
  return 1.0f / (1.0f + expf(-x));
}
// order-preserving float->uint encoding for atomicMax
static __device__ __forceinline__ unsigned enc_f(float f) {
  unsigned u = __float_as_uint(f);
  return (u >> 31) ? ~u : (u | 0x80000000u);
}
static __device__ __forceinline__ float dec_f(unsigned e) {
  return (e >> 31) ? __uint_as_float(e ^ 0x80000000u) : __uint_as_float(~e);
}

__global__ void k_init(unsigned* gmax, uint64_t* flags, int* nvalid, int* lhist, int* ecnt) {
  int t = blockIdx.x * 256 + threadIdx.x;
  int NT = gridDim.x * 256;
  for (int k = t; k < NIMG * NW; k += NT) flags[k] = 0ull;     // 4.2 KB
  for (int k = t; k < NIMG * NCLS; k += NT) lhist[k] = 0;
  if (t < NIMG) { gmax[t] = 0u; nvalid[t] = 0; ecnt[t] = 0; }
}

// ---------------- decode: 4 threads/point x 20 classes; sigmoid argmax + box decode
__global__ __launch_bounds__(256) void k_decode(
    const float* __restrict__ cls0, const float* __restrict__ cls1, const float* __restrict__ cls2,
    const float* __restrict__ reg0, const float* __restrict__ reg1, const float* __restrict__ reg2,
    const float* __restrict__ obj0, const float* __restrict__ obj1, const float* __restrict__ obj2,
    float* __restrict__ score, int* __restrict__ label, float* __restrict__ boxes,
    unsigned* __restrict__ gmax, int* __restrict__ lhist)
{
  int t = blockIdx.x * 256 + threadIdx.x;   // 525 blocks * 256 == NIMG*PTOT*4 exactly
  int n = t / (PTOT * 4);
  int rem = t - n * (PTOT * 4);
  int p = rem >> 2, q = rem & 3;            // 4 consecutive lanes share one point
  const float* cb; const float* rb; const float* ob;
  int HW, W, pl; float s;
  if (p < 6400)      { cb = cls0; rb = reg0; ob = obj0; HW = 6400; W = 80; pl = p;        s = 8.f;  }
  else if (p < 8000) { cb = cls1; rb = reg1; ob = obj1; HW = 1600; W = 40; pl = p - 6400; s = 16.f; }
  else               { cb = cls2; rb = reg2; ob = obj2; HW = 400;  W = 20; pl = p - 8000; s = 32.f; }

  // partial argmax over 20 sigmoid(cls) values (first-max-wins within quarter)
  const float* cp = cb + (size_t)n * NCLS * HW + pl;
  float best = -1.0f; int bi = 0;
#pragma unroll
  for (int cc = 0; cc < 20; ++cc) {
    int c = q * 20 + cc;
    float v = sigmoidf_(cp[(size_t)c * HW]);
    if (v > best) { best = v; bi = c; }
  }
  // merge quarters; lower class index wins ties (replicates jnp.argmax first-max)
  {
    float ob_ = __shfl_xor(best, 1, 64); int oi = __shfl_xor(bi, 1, 64);
    float bl, bh; int il, ih;
    if ((q & 1) == 0) { bl = best; il = bi; bh = ob_; ih = oi; }
    else              { bl = ob_;  il = oi; bh = best; ih = bi; }
    if (bh > bl) { best = bh; bi = ih; } else { best = bl; bi = il; }
  }
  {
    float ob_ = __shfl_xor(best, 2, 64); int oi = __shfl_xor(bi, 2, 64);
    float bl, bh; int il, ih;
    if ((q & 2) == 0) { bl = best; il = bi; bh = ob_; ih = oi; }
    else              { bl = ob_;  il = oi; bh = best; ih = bi; }
    if (bh > bl) { best = bh; bi = ih; } else { best = bl; bi = il; }
  }

  float m = -3.4e38f;
  if (q == 0) {
    float osg = sigmoidf_(ob[(size_t)n * HW + pl]);
    float sc = best * osg;
    const float* rp = rb + (size_t)n * 4 * HW + pl;
    float rx = rp[0], ry = rp[(size_t)HW], rw = rp[(size_t)2 * HW], rh = rp[(size_t)3 * HW];
    int ph = pl / W, pw = pl - ph * W;
    float cx = rx * s + (float)pw * s, cy = ry * s + (float)ph * s;
    float bw = expf(rw) * s, bh2 = expf(rh) * s;
    float x1 = cx - bw * 0.5f, y1 = cy - bh2 * 0.5f;
    float x2 = cx + bw * 0.5f, y2 = cy + bh2 * 0.5f;
    int g = n * PTOT + p;
    score[g] = sc;
    label[g] = bi;
    atomicAdd(&lhist[n * NCLS + bi], 1);
    float* bx = boxes + (size_t)g * 4;
    bx[0] = x1; bx[1] = y1; bx[2] = x2; bx[3] = y2;
    m = fmaxf(fmaxf(x1, y1), fmaxf(x2, y2));
  }
  // wave max (wave is single-image: 33600 % 64 == 0)
  for (int o = 32; o; o >>= 1) m = fmaxf(m, __shfl_xor(m, o, 64));
  if ((threadIdx.x & 63) == 0) atomicMax(&gmax[n], enc_f(m));
}

// ---------------- per-image stable LSD radix sort (8 x 4-bit) -> rank permutation
// (verified R8 structure: packed-register counters, shfl wave scan)
__global__ __launch_bounds__(256) void k_sort(
    const float* __restrict__ score, int* __restrict__ rank,
    const int* __restrict__ lhist, int* __restrict__ bstart, int* __restrict__ cursor)
{
  __shared__ uint32_t A[NPAD];        // 33.8 KB keys
  __shared__ uint16_t Pp[NPAD];       // 16.9 KB payload (orig index)
  __shared__ uint16_t hist[16 * 256]; // 8 KB (slot f = d*256+t)
  __shared__ uint32_t part[256];      // 1 KB group exclusive prefixes
  __shared__ uint32_t wsum[4];
  int n = blockIdx.x, t = threadIdx.x;
  const float* sc = score + (size_t)n * PTOT;
  for (int i = t; i < PTOT; i += 256) {
    float v = sc[i];
    float key = (v >= SCORE_THR_C) ? v : -1.0f;
    A[i] = ~enc_f(key);
    Pp[i] = (uint16_t)i;
  }
  for (int i = PTOT + t; i < NPAD; i += 256) {
    A[i] = 0xFFFFFFFFu;               // sorts strictly last
    Pp[i] = (uint16_t)i;
  }
  __syncthreads();
  const int base0 = t * 33;           // 256*33 == NPAD
  for (int pass = 0; pass < 8; ++pass) {
    const int sh = pass * 4;
    uint32_t k[33]; uint16_t p[33];
#pragma unroll
    for (int e = 0; e < 33; ++e) { k[e] = A[base0 + e]; p[e] = Pp[base0 + e]; }
    uint64_t c0 = 0, c1 = 0;
#pragma unroll
    for (int e = 0; e < 33; ++e) {
      uint32_t d = (k[e] >> sh) & 15u;
      uint64_t inc = 1ull << ((d & 7u) << 3);
      if (d < 8) c0 += inc; else c1 += inc;
    }
#pragma unroll
    for (int d = 0; d < 16; ++d) {
      uint32_t cnt = (uint32_t)(((d < 8) ? (c0 >> (d * 8)) : (c1 >> ((d - 8) * 8))) & 0xFFull);
      hist[d * 256 + t] = (uint16_t)cnt;
    }
    __syncthreads();
    uint32_t s = 0;
#pragma unroll
    for (int qq = 0; qq < 16; ++qq) {
      int f = t * 16 + qq;
      uint32_t h = hist[f];
      hist[f] = (uint16_t)s;
      s += h;
    }
    uint32_t v = s;
#pragma unroll
    for (int off = 1; off < 64; off <<= 1) {
      uint32_t u = __shfl_up(v, off, 64);
      if ((t & 63) >= off) v += u;
    }
    if ((t & 63) == 63) wsum[t >> 6] = v;
    __syncthreads();
    uint32_t wpre = 0;
#pragma unroll
    for (int wv = 0; wv < 4; ++wv) wpre += (wv < (t >> 6)) ? wsum[wv] : 0;
    part[t] = v - s + wpre;
    __syncthreads();
    uint64_t cc0 = 0, cc1 = 0;
#pragma unroll
    for (int e = 0; e < 33; ++e) {
      uint32_t d = (k[e] >> sh) & 15u;
      int f = d * 256 + t;
      uint32_t within = (uint32_t)(((d < 8) ? (cc0 >> ((d & 7u) << 3))
                                            : (cc1 >> ((d & 7u) << 3))) & 0xFFull);
      uint32_t pos = (uint32_t)hist[f] + part[f >> 4] + within;
      A[pos] = k[e];
      Pp[pos] = p[e];
      uint64_t inc = 1ull << ((d & 7u) << 3);
      if (d < 8) cc0 += inc; else cc1 += inc;
    }
    __syncthreads();
  }
  for (int pos = t; pos < PTOT; pos += 256)
    rank[(size_t)n * PTOT + Pp[pos]] = pos;
  if (t == 0) {
    int acc = 0;
    for (int L = 0; L < NCLS; ++L) { bstart[n * (NCLS + 1) + L] = acc; acc += lhist[n * NCLS + L]; }
    bstart[n * (NCLS + 1) + NCLS] = acc;
  }
  __syncthreads();
  if (t < NCLS) cursor[n * NCLS + t] = bstart[n * (NCLS + 1) + t];
}

// ---------------- scatter into sorted order + shifted boxes/areas + nvalid + bucket fill
__global__ __launch_bounds__(256) void k_scatter(
    const float* __restrict__ score, const int* __restrict__ label, const float* __restrict__ boxes,
    const unsigned* __restrict__ gmax, const int* __restrict__ rank, int* __restrict__ nvalid,
    float* __restrict__ s_score, int* __restrict__ s_label,
    float* __restrict__ s_box, float* __restrict__ s_sbox, float* __restrict__ s_area,
    int* __restrict__ cursor, int* __restrict__ bidx)
{
  int n = blockIdx.y;
  int i = blockIdx.x * 256 + threadIdx.x;
  if (i >= PTOT) return;
  const float* sc = score + (size_t)n * PTOT;
  float v = sc[i];
  bool valid = (v >= SCORE_THR_C);
  unsigned long long bal = __ballot(valid);
  if ((threadIdx.x & 63) == 0) atomicAdd(&nvalid[n], (int)__popcll(bal));

  int r = rank[(size_t)n * PTOT + i];  // stable permutation
  float gm = dec_f(gmax[n]);
  int li = label[(size_t)n * PTOT + i];
  const float* bp = boxes + ((size_t)n * PTOT + i) * 4;
  float b0 = bp[0], b1 = bp[1], b2 = bp[2], b3 = bp[3];
  float off = (float)li * (gm + 1.0f);
  float q0 = b0 + off, q1 = b1 + off, q2 = b2 + off, q3 = b3 + off;
  float area = (q2 - q0) * (q3 - q1);   // area from SHIFTED coords (matches reference)

  size_t d = (size_t)n * PTOT + (size_t)r;
  s_score[d] = v;
  s_label[d] = li;
  float* sb = s_box + d * 4;  sb[0] = b0; sb[1] = b1; sb[2] = b2; sb[3] = b3;
  float* sq = s_sbox + d * 4; sq[0] = q0; sq[1] = q1; sq[2] = q2; sq[3] = q3;
  s_area[d] = area;
  int pos = atomicAdd(&cursor[n * NCLS + li], 1);
  bidx[(size_t)n * PTOT + pos] = r;
}

// ---------------- sparse pair IoU -> edge list (i<<16|j, i<j) + per-row flags
__global__ __launch_bounds__(256) void k_pairs(
    const float* __restrict__ s_sbox, const float* __restrict__ s_area,
    const int* __restrict__ bstart, const int* __restrict__ bidx,
    uint32_t* __restrict__ eb, int* __restrict__ ecnt, uint64_t* __restrict__ flags)
{
  int n = blockIdx.z, L = blockIdx.x, d = blockIdx.y;
  int L2 = L + d;
  if (L2 >= NCLS) return;
  const int* bs = bstart + n * (NCLS + 1);
  int a0 = bs[L], a1 = bs[L + 1];
  int b0 = bs[L2], b1 = bs[L2 + 1];
  int na = a1 - a0, nb = b1 - b0;
  if (na == 0 || nb == 0) return;
  const int* ba = bidx + (size_t)n * PTOT + a0;
  const int* bb = bidx + (size_t)n * PTOT + b0;
  const float4* SB = (const float4*)(s_sbox + (size_t)n * PTOT * 4);
  const float* SA = s_area + (size_t)n * PTOT;
  int tot = na * nb;
  for (int t = threadIdx.x; t < tot; t += 256) {
    int u = t / nb, v = t - u * nb;
    if (d == 0 && u >= v) continue;          // unordered within-bucket pairs
    int p = ba[u], q = bb[v];
    float4 A = SB[p], B = SB[q];
    float ww = fminf(A.z, B.z) - fmaxf(A.x, B.x);
    float hh = fminf(A.w, B.w) - fmaxf(A.y, B.y);
    if (ww <= 0.0f || hh <= 0.0f) continue;  // inter=0 -> iou=0 -> no edge (exact)
    float inter = ww * hh;
    float aa = SA[p], ab = SA[q];
    float uni = fmaxf(aa + ab - inter, 1e-12f);
    if (inter / uni > NMS_THR_C) {           // identical arithmetic to reference
      uint32_t i = (uint32_t)min(p, q), j = (uint32_t)max(p, q);
      int idx = atomicAdd(&ecnt[n], 1);
      if (idx < ECAP) eb[(size_t)n * ECAP + idx] = (i << 16) | j;
      atomicOr((unsigned long long*)&flags[(size_t)n * NW + (i >> 6)], 1ull << (i & 63u));
    }
  }
}

// ---------------- greedy suppression: event-driven over edge list, LDS removed-bitmask
__global__ __launch_bounds__(64) void k_scan(
    const uint32_t* __restrict__ eb, const int* __restrict__ ecnt,
    const uint64_t* __restrict__ flags, const int* __restrict__ nvalid,
    uint64_t* __restrict__ keepw)
{
  __shared__ uint64_t Rm[NW];   // removed bitmask
  __shared__ uint64_t Fl[NW];   // rows-with-edges bitmap
  int n = blockIdx.x, l = threadIdx.x;
  int nv = nvalid[n];
  auto initw = [&](int w) -> uint64_t {
    int base = w * 64;
    if (nv <= base) return ~0ull;
    if (nv >= base + 64) return 0ull;
    return (~0ull) << (nv - base);
  };
  const uint64_t* fl = flags + (size_t)n * NW;
  uint64_t f0 = fl[l], f1 = fl[64 + l], f2 = (l < 4) ? fl[128 + l] : 0ull;
  Rm[l] = initw(l); Rm[64 + l] = initw(64 + l);
  if (l < 4) Rm[128 + l] = initw(128 + l);
  Fl[l] = f0; Fl[64 + l] = f1;
  if (l < 4) Fl[128 + l] = f2;
  uint64_t nzc0 = __ballot(f0 != 0ull);                 // chunks 0..63 with events
  uint64_t nzc1 = __ballot(f1 != 0ull);                 // 64..127
  uint64_t nzc2 = __ballot((l < 4) && (f2 != 0ull));    // 128..131
  int cnt = ecnt[n]; if (cnt > ECAP) cnt = ECAP;
  const uint32_t* E = eb + (size_t)n * ECAP;
  uint32_t Er[16];
#pragma unroll
  for (int s = 0; s < 16; ++s) {
    int k = s * 64 + l;
    Er[s] = (k < cnt) ? E[k] : 0xFFFFFFFFu;             // sentinel never matches
  }
  // single wave: LDS ops ordered via lgkmcnt; no barriers needed
  for (int seg = 0; seg < 3; ++seg) {
    uint64_t bm = (seg == 0) ? nzc0 : (seg == 1) ? nzc1 : nzc2;
    int cb = seg * 64;
    while (bm) {
      int c = cb + __builtin_ctzll(bm); bm &= bm - 1;
      uint64_t F = Fl[c];                               // uniform broadcast read
      while (F) {
        int b = __builtin_ctzll(F); F &= F - 1;
        uint64_t cur = Rm[c];                           // fresh (in-chunk updates visible)
        if ((cur >> b) & 1ull) continue;                // row already suppressed
        uint32_t i = (uint32_t)(c * 64 + b);
        // apply row i: all lanes scan their register edges for i-matches
#pragma unroll
        for (int s = 0; s < 16; ++s) {
          uint32_t e = Er[s];
          if ((e >> 16) == i) {
            uint32_t j = e & 0xFFFFu;                   // j > i always (k_pairs)
            atomicOr((unsigned long long*)&Rm[j >> 6], 1ull << (j & 63u));
          }
        }
        if (cnt > ERCAP) {                              // emergency overflow path
          for (int k = ERCAP + l; k < cnt; k += 64) {
            uint32_t e = E[k];
            if ((e >> 16) == i) {
              uint32_t j = e & 0xFFFFu;
              atomicOr((unsigned long long*)&Rm[j >> 6], 1ull << (j & 63u));
            }
          }
        }
      }
    }
  }
  keepw[(size_t)n * NW + l] = ~Rm[l];
  keepw[(size_t)n * NW + 64 + l] = ~Rm[64 + l];
  if (l < 4) keepw[(size_t)n * NW + 128 + l] = ~Rm[128 + l];
}

// ---------------- finalize outputs
__global__ __launch_bounds__(256) void k_final(
    const float* __restrict__ s_score, const int* __restrict__ s_label,
    const float* __restrict__ s_box, const uint64_t* __restrict__ keepw,
    float* __restrict__ out)
{
  int t = blockIdx.x * 256 + threadIdx.x;
  if (t >= NIMG * PTOT) return;
  int n = t / PTOT, p = t - n * PTOT;
  uint64_t w = keepw[(size_t)n * NW + (p >> 6)];
  float k = (float)((w >> (p & 63)) & 1ull);
  float* dets = out;
  float* lab  = out + (size_t)NIMG * PTOT * 5;
  float* kp   = out + (size_t)NIMG * PTOT * 6;
  const float* bp = s_box + (size_t)t * 4;
  float* dp = dets + (size_t)t * 5;
  dp[0] = bp[0] * k; dp[1] = bp[1] * k; dp[2] = bp[2] * k; dp[3] = bp[3] * k;
  dp[4] = s_score[t] * k;
  lab[t] = (float)s_label[t];
  kp[t]  = k;
}

extern "C" void kernel_launch(void* const* d_in, const int* in_sizes, int n_in,
                              void* d_out, int out_size, void* d_ws, size_t ws_size,
                              hipStream_t stream)
{
  const float* cls0 = (const float*)d_in[0];
  const float* cls1 = (const float*)d_in[1];
  const float* cls2 = (const float*)d_in[2];
  const float* reg0 = (const float*)d_in[3];
  const float* reg1 = (const float*)d_in[4];
  const float* reg2 = (const float*)d_in[5];
  const float* obj0 = (const float*)d_in[6];
  const float* obj1 = (const float*)d_in[7];
  const float* obj2 = (const float*)d_in[8];

  char* w = (char*)d_ws;
  uint64_t* keepw = (uint64_t*)w; w += (size_t)NIMG * NW * 8;          // 4,224 B
  uint64_t* flags = (uint64_t*)w; w += (size_t)NIMG * NW * 8;          // 4,224 B
  float* score = (float*)w;       w += (size_t)NIMG * PTOT * 4;
  int*   label = (int*)w;         w += (size_t)NIMG * PTOT * 4;
  float* boxes = (float*)w;       w += (size_t)NIMG * PTOT * 16;
  float* ss = (float*)w;          w += (size_t)NIMG * PTOT * 4;
  int*   sl = (int*)w;            w += (size_t)NIMG * PTOT * 4;
  float* sb = (float*)w;          w += (size_t)NIMG * PTOT * 16;
  float* sq = (float*)w;          w += (size_t)NIMG * PTOT * 16;
  float* sa = (float*)w;          w += (size_t)NIMG * PTOT * 4;
  unsigned* gmax = (unsigned*)w;  w += 256;
  int* nvalid = (int*)w;          w += 256;
  int* rank = (int*)w;            w += (size_t)NIMG * PTOT * 4;
  int* lhist = (int*)w;           w += (size_t)NIMG * NCLS * 4;        // 1,280 B
  int* bstart = (int*)w;          w += (size_t)NIMG * (NCLS + 1) * 4;  // 1,296 B
  int* cursor = (int*)w;          w += (size_t)NIMG * NCLS * 4;
  int* bidx = (int*)w;            w += (size_t)NIMG * PTOT * 4;
  uint32_t* eb = (uint32_t*)w;    w += (size_t)NIMG * ECAP * 4;        // 1 MB
  int* ecnt = (int*)w;            w += 256;

  k_init<<<dim3(4), dim3(256), 0, stream>>>(gmax, flags, nvalid, lhist, ecnt);
  k_decode<<<dim3((NIMG * PTOT * 4) / 256), dim3(256), 0, stream>>>(
      cls0, cls1, cls2, reg0, reg1, reg2, obj0, obj1, obj2,
      score, label, boxes, gmax, lhist);
  k_sort<<<dim3(NIMG), dim3(256), 0, stream>>>(score, rank, lhist, bstart, cursor);
  k_scatter<<<dim3((PTOT + 255) / 256, NIMG), dim3(256), 0, stream>>>(
      score, label, boxes, gmax, rank, nvalid, ss, sl, sb, sq, sa, cursor, bidx);
  k_pairs<<<dim3(NCLS, DMAX + 1, NIMG), dim3(256), 0, stream>>>(
      sq, sa, bstart, bidx, eb, ecnt, flags);
  k_scan<<<dim3(NIMG), dim3(64), 0, stream>>>(eb, ecnt, flags, nvalid, keepw);
  k_final<<<dim3((NIMG * PTOT + 255) / 256), dim3(256), 0, stream>>>(
      ss, sl, sb, keepw, (float*)d_out);
}

// Round 10
// 196.739 us; speedup vs baseline: 7.8097x; 1.0633x over previous
//
#include <hip/hip_runtime.h>
#include <stdint.h>

#define NIMG 4
#define PTOT 8400
#define NCLS 80
#define NW   132            // 64-bit words per removed-bitmask row (ceil(8400/64))
#define DMAX 3              // static upper bound on label distance (dynamic check tightens)
#define NPAD 8448           // padded sort size (= 256 threads * 33)
#define ECAP 65536          // edge buffer capacity per image (expected ~150)
#define ERCAP 1024          // register-resident edge fast path (16 slots x 64 lanes)
#define PTILE 512           // LDS box tile for pair enumeration
#define NMS_THR_C 0.65f
#define SCORE_THR_C 0.01f

static __device__ __forceinline__ float sigmoidf_(float x) {
  return 1.0f / (1.0f + expf(-x));
}
// order-preserving float->uint encoding for atomicMax/Min
static __device__ __forceinline__ unsigned enc_f(float f) {
  unsigned u = __float_as_uint(f);
  return (u >> 31) ? ~u : (u | 0x80000000u);
}
static __device__ __forceinline__ float dec_f(unsigned e) {
  return (e >> 31) ? __uint_as_float(e ^ 0x80000000u) : __uint_as_float(~e);
}

__global__ void k_init(unsigned* gmax, unsigned* gmin, uint64_t* flags, int* nvalid,
                       int* lhist, int* ecnt) {
  int t = blockIdx.x * 256 + threadIdx.x;
  int NT = gridDim.x * 256;
  for (int k = t; k < NIMG * NW; k += NT) flags[k] = 0ull;     // 4.2 KB
  for (int k = t; k < NIMG * NCLS; k += NT) lhist[k] = 0;
  if (t < NIMG) { gmax[t] = 0u; gmin[t] = 0xFFFFFFFFu; nvalid[t] = 0; ecnt[t] = 0; }
}

// ---------------- decode: 4 threads/point x 20 classes; sigmoid argmax + box decode
__global__ __launch_bounds__(256) void k_decode(
    const float* __restrict__ cls0, const float* __restrict__ cls1, const float* __restrict__ cls2,
    const float* __restrict__ reg0, const float* __restrict__ reg1, const float* __restrict__ reg2,
    const float* __restrict__ obj0, const float* __restrict__ obj1, const float* __restrict__ obj2,
    float* __restrict__ score, int* __restrict__ label, float* __restrict__ boxes,
    unsigned* __restrict__ gmax, unsigned* __restrict__ gmin, int* __restrict__ lhist)
{
  int t = blockIdx.x * 256 + threadIdx.x;   // 525 blocks * 256 == NIMG*PTOT*4 exactly
  int n = t / (PTOT * 4);
  int rem = t - n * (PTOT * 4);
  int p = rem >> 2, q = rem & 3;            // 4 consecutive lanes share one point
  const float* cb; const float* rb; const float* ob;
  int HW, W, pl; float s;
  if (p < 6400)      { cb = cls0; rb = reg0; ob = obj0; HW = 6400; W = 80; pl = p;        s = 8.f;  }
  else if (p < 8000) { cb = cls1; rb = reg1; ob = obj1; HW = 1600; W = 40; pl = p - 6400; s = 16.f; }
  else               { cb = cls2; rb = reg2; ob = obj2; HW = 400;  W = 20; pl = p - 8000; s = 32.f; }

  // partial argmax over 20 sigmoid(cls) values (first-max-wins within quarter)
  const float* cp = cb + (size_t)n * NCLS * HW + pl;
  float best = -1.0f; int bi = 0;
#pragma unroll
  for (int cc = 0; cc < 20; ++cc) {
    int c = q * 20 + cc;
    float v = sigmoidf_(cp[(size_t)c * HW]);
    if (v > best) { best = v; bi = c; }
  }
  // merge quarters; lower class index wins ties (replicates jnp.argmax first-max)
  {
    float ob_ = __shfl_xor(best, 1, 64); int oi = __shfl_xor(bi, 1, 64);
    float bl, bh; int il, ih;
    if ((q & 1) == 0) { bl = best; il = bi; bh = ob_; ih = oi; }
    else              { bl = ob_;  il = oi; bh = best; ih = bi; }
    if (bh > bl) { best = bh; bi = ih; } else { best = bl; bi = il; }
  }
  {
    float ob_ = __shfl_xor(best, 2, 64); int oi = __shfl_xor(bi, 2, 64);
    float bl, bh; int il, ih;
    if ((q & 2) == 0) { bl = best; il = bi; bh = ob_; ih = oi; }
    else              { bl = ob_;  il = oi; bh = best; ih = bi; }
    if (bh > bl) { best = bh; bi = ih; } else { best = bl; bi = il; }
  }

  float m = -3.4e38f, m2 = 3.4e38f;
  if (q == 0) {
    float osg = sigmoidf_(ob[(size_t)n * HW + pl]);
    float sc = best * osg;
    const float* rp = rb + (size_t)n * 4 * HW + pl;
    float rx = rp[0], ry = rp[(size_t)HW], rw = rp[(size_t)2 * HW], rh = rp[(size_t)3 * HW];
    int ph = pl / W, pw = pl - ph * W;
    float cx = rx * s + (float)pw * s, cy = ry * s + (float)ph * s;
    float bw = expf(rw) * s, bh2 = expf(rh) * s;
    float x1 = cx - bw * 0.5f, y1 = cy - bh2 * 0.5f;
    float x2 = cx + bw * 0.5f, y2 = cy + bh2 * 0.5f;
    int g = n * PTOT + p;
    score[g] = sc;
    label[g] = bi;
    atomicAdd(&lhist[n * NCLS + bi], 1);
    float* bx = boxes + (size_t)g * 4;
    bx[0] = x1; bx[1] = y1; bx[2] = x2; bx[3] = y2;
    m = fmaxf(x2, y2);        // max coord (x2>x1, y2>y1 always: bw,bh>0)
    m2 = fminf(x1, y1);       // min coord
  }
  // wave reduces (wave is single-image: 33600 % 64 == 0)
  for (int o = 32; o; o >>= 1) {
    m = fmaxf(m, __shfl_xor(m, o, 64));
    m2 = fminf(m2, __shfl_xor(m2, o, 64));
  }
  if ((threadIdx.x & 63) == 0) {
    atomicMax(&gmax[n], enc_f(m));
    atomicMin(&gmin[n], enc_f(m2));
  }
}

// ---------------- per-image stable LSD radix sort (8 x 4-bit) -> rank permutation
// (verified R8 structure: packed-register counters, shfl wave scan)
__global__ __launch_bounds__(256) void k_sort(
    const float* __restrict__ score, int* __restrict__ rank,
    const int* __restrict__ lhist, int* __restrict__ bstart, int* __restrict__ cursor)
{
  __shared__ uint32_t A[NPAD];        // 33.8 KB keys
  __shared__ uint16_t Pp[NPAD];       // 16.9 KB payload (orig index)
  __shared__ uint16_t hist[16 * 256]; // 8 KB (slot f = d*256+t)
  __shared__ uint32_t part[256];      // 1 KB group exclusive prefixes
  __shared__ uint32_t wsum[4];
  int n = blockIdx.x, t = threadIdx.x;
  const float* sc = score + (size_t)n * PTOT;
  for (int i = t; i < PTOT; i += 256) {
    float v = sc[i];
    float key = (v >= SCORE_THR_C) ? v : -1.0f;
    A[i] = ~enc_f(key);
    Pp[i] = (uint16_t)i;
  }
  for (int i = PTOT + t; i < NPAD; i += 256) {
    A[i] = 0xFFFFFFFFu;               // sorts strictly last
    Pp[i] = (uint16_t)i;
  }
  __syncthreads();
  const int base0 = t * 33;           // 256*33 == NPAD
  for (int pass = 0; pass < 8; ++pass) {
    const int sh = pass * 4;
    uint32_t k[33]; uint16_t p[33];
#pragma unroll
    for (int e = 0; e < 33; ++e) { k[e] = A[base0 + e]; p[e] = Pp[base0 + e]; }
    uint64_t c0 = 0, c1 = 0;
#pragma unroll
    for (int e = 0; e < 33; ++e) {
      uint32_t d = (k[e] >> sh) & 15u;
      uint64_t inc = 1ull << ((d & 7u) << 3);
      if (d < 8) c0 += inc; else c1 += inc;
    }
#pragma unroll
    for (int d = 0; d < 16; ++d) {
      uint32_t cnt = (uint32_t)(((d < 8) ? (c0 >> (d * 8)) : (c1 >> ((d - 8) * 8))) & 0xFFull);
      hist[d * 256 + t] = (uint16_t)cnt;
    }
    __syncthreads();
    uint32_t s = 0;
#pragma unroll
    for (int qq = 0; qq < 16; ++qq) {
      int f = t * 16 + qq;
      uint32_t h = hist[f];
      hist[f] = (uint16_t)s;
      s += h;
    }
    uint32_t v = s;
#pragma unroll
    for (int off = 1; off < 64; off <<= 1) {
      uint32_t u = __shfl_up(v, off, 64);
      if ((t & 63) >= off) v += u;
    }
    if ((t & 63) == 63) wsum[t >> 6] = v;
    __syncthreads();
    uint32_t wpre = 0;
#pragma unroll
    for (int wv = 0; wv < 4; ++wv) wpre += (wv < (t >> 6)) ? wsum[wv] : 0;
    part[t] = v - s + wpre;
    __syncthreads();
    uint64_t cc0 = 0, cc1 = 0;
#pragma unroll
    for (int e = 0; e < 33; ++e) {
      uint32_t d = (k[e] >> sh) & 15u;
      int f = d * 256 + t;
      uint32_t within = (uint32_t)(((d < 8) ? (cc0 >> ((d & 7u) << 3))
                                            : (cc1 >> ((d & 7u) << 3))) & 0xFFull);
      uint32_t pos = (uint32_t)hist[f] + part[f >> 4] + within;
      A[pos] = k[e];
      Pp[pos] = p[e];
      uint64_t inc = 1ull << ((d & 7u) << 3);
      if (d < 8) cc0 += inc; else cc1 += inc;
    }
    __syncthreads();
  }
  for (int pos = t; pos < PTOT; pos += 256)
    rank[(size_t)n * PTOT + Pp[pos]] = pos;
  if (t == 0) {
    int acc = 0;
    for (int L = 0; L < NCLS; ++L) { bstart[n * (NCLS + 1) + L] = acc; acc += lhist[n * NCLS + L]; }
    bstart[n * (NCLS + 1) + NCLS] = acc;
  }
  __syncthreads();
  if (t < NCLS) cursor[n * NCLS + t] = bstart[n * (NCLS + 1) + t];
}

// ---------------- scatter into sorted order + shifted boxes/areas + nvalid + bucket fill
__global__ __launch_bounds__(256) void k_scatter(
    const float* __restrict__ score, const int* __restrict__ label, const float* __restrict__ boxes,
    const unsigned* __restrict__ gmax, const int* __restrict__ rank, int* __restrict__ nvalid,
    float* __restrict__ s_score, int* __restrict__ s_label,
    float* __restrict__ s_box, float* __restrict__ s_sbox, float* __restrict__ s_area,
    int* __restrict__ cursor, int* __restrict__ bidx)
{
  int n = blockIdx.y;
  int i = blockIdx.x * 256 + threadIdx.x;
  if (i >= PTOT) return;
  const float* sc = score + (size_t)n * PTOT;
  float v = sc[i];
  bool valid = (v >= SCORE_THR_C);
  unsigned long long bal = __ballot(valid);
  if ((threadIdx.x & 63) == 0) atomicAdd(&nvalid[n], (int)__popcll(bal));

  int r = rank[(size_t)n * PTOT + i];  // stable permutation
  float gm = dec_f(gmax[n]);
  int li = label[(size_t)n * PTOT + i];
  const float* bp = boxes + ((size_t)n * PTOT + i) * 4;
  float b0 = bp[0], b1 = bp[1], b2 = bp[2], b3 = bp[3];
  float off = (float)li * (gm + 1.0f);
  float q0 = b0 + off, q1 = b1 + off, q2 = b2 + off, q3 = b3 + off;
  float area = (q2 - q0) * (q3 - q1);   // area from SHIFTED coords (matches reference)

  size_t d = (size_t)n * PTOT + (size_t)r;
  s_score[d] = v;
  s_label[d] = li;
  float* sb = s_box + d * 4;  sb[0] = b0; sb[1] = b1; sb[2] = b2; sb[3] = b3;
  float* sq = s_sbox + d * 4; sq[0] = q0; sq[1] = q1; sq[2] = q2; sq[3] = q3;
  s_area[d] = area;
  int pos = atomicAdd(&cursor[n * NCLS + li], 1);
  bidx[(size_t)n * PTOT + pos] = r;
}

// ---------------- sparse pair IoU -> edge list; LDS box tiles, dynamic slab distance
__global__ __launch_bounds__(256) void k_pairs(
    const float* __restrict__ s_sbox, const float* __restrict__ s_area,
    const int* __restrict__ bstart, const int* __restrict__ bidx,
    const unsigned* __restrict__ gmax, const unsigned* __restrict__ gmin,
    uint32_t* __restrict__ eb, int* __restrict__ ecnt, uint64_t* __restrict__ flags)
{
  int n = blockIdx.z, L = blockIdx.x, d = blockIdx.y;
  int L2 = L + d;
  if (L2 >= NCLS) return;
  if (d > 0) {
    // slabs [off+m, off+g] at distance d(g+1) can't overlap when d(g+1) > g-m
    // (+1.0f slack makes float rounding err only toward extra exact work)
    float gm = dec_f(gmax[n]), gmn = dec_f(gmin[n]);
    if ((float)d * (gm + 1.0f) > (gm - gmn) + 1.0f) return;
  }
  const int* bs = bstart + n * (NCLS + 1);
  int a0 = bs[L], na = bs[L + 1] - a0;
  int b0 = bs[L2], nb = bs[L2 + 1] - b0;
  if (na == 0 || nb == 0) return;
  const int* ba = bidx + (size_t)n * PTOT + a0;
  const int* bb = bidx + (size_t)n * PTOT + b0;
  const float4* SB = (const float4*)(s_sbox + (size_t)n * PTOT * 4);
  const float* SA = s_area + (size_t)n * PTOT;

  __shared__ float4 lA[PTILE]; __shared__ float lAa[PTILE]; __shared__ int liA[PTILE];
  __shared__ float4 lB[PTILE]; __shared__ float lBa[PTILE]; __shared__ int liB[PTILE];
  int tid = threadIdx.x;

  for (int ub = 0; ub < na; ub += PTILE) {
    int ua = min(PTILE, na - ub);
    for (int i = tid; i < ua; i += 256) {        // stage A tile (gather once per box)
      int p = ba[ub + i];
      liA[i] = p; lA[i] = SB[p]; lAa[i] = SA[p];
    }
    for (int vb = 0; vb < nb; vb += PTILE) {
      int va = min(PTILE, nb - vb);
      for (int i = tid; i < va; i += 256) {      // stage B tile
        int p = bb[vb + i];
        liB[i] = p; lB[i] = SB[p]; lBa[i] = SA[p];
      }
      __syncthreads();
      for (int u = 0; u < ua; ++u) {
        float4 A = lA[u]; float aa = lAa[u]; int p = liA[u];   // LDS broadcast
        int vstart = 0;
        if (d == 0) { vstart = (ub + u) + 1 - vb; if (vstart < 0) vstart = 0; }
        for (int v = vstart + tid; v < va; v += 256) {
          float4 B = lB[v];
          float ww = fminf(A.z, B.z) - fmaxf(A.x, B.x);
          float hh = fminf(A.w, B.w) - fmaxf(A.y, B.y);
          if (ww <= 0.0f || hh <= 0.0f) continue;  // inter=0 -> iou=0 -> no edge (exact)
          float inter = ww * hh;
          float uni = fmaxf(aa + lBa[v] - inter, 1e-12f);
          if (inter / uni > NMS_THR_C) {           // identical arithmetic to reference
            uint32_t q = (uint32_t)liB[v];
            uint32_t i_ = min((uint32_t)p, q), j_ = max((uint32_t)p, q);
            int idx = atomicAdd(&ecnt[n], 1);
            if (idx < ECAP) eb[(size_t)n * ECAP + idx] = (i_ << 16) | j_;
            atomicOr((unsigned long long*)&flags[(size_t)n * NW + (i_ >> 6)], 1ull << (i_ & 63u));
          }
        }
      }
      __syncthreads();
    }
  }
}

// ---------------- greedy suppression: event-driven over edge list, LDS removed-bitmask
__global__ __launch_bounds__(64) void k_scan(
    const uint32_t* __restrict__ eb, const int* __restrict__ ecnt,
    const uint64_t* __restrict__ flags, const int* __restrict__ nvalid,
    uint64_t* __restrict__ keepw)
{
  __shared__ uint64_t Rm[NW];   // removed bitmask
  __shared__ uint64_t Fl[NW];   // rows-with-edges bitmap
  int n = blockIdx.x, l = threadIdx.x;
  int nv = nvalid[n];
  auto initw = [&](int w) -> uint64_t {
    int base = w * 64;
    if (nv <= base) return ~0ull;
    if (nv >= base + 64) return 0ull;
    return (~0ull) << (nv - base);
  };
  const uint64_t* fl = flags + (size_t)n * NW;
  uint64_t f0 = fl[l], f1 = fl[64 + l], f2 = (l < 4) ? fl[128 + l] : 0ull;
  Rm[l] = initw(l); Rm[64 + l] = initw(64 + l);
  if (l < 4) Rm[128 + l] = initw(128 + l);
  Fl[l] = f0; Fl[64 + l] = f1;
  if (l < 4) Fl[128 + l] = f2;
  uint64_t nzc0 = __ballot(f0 != 0ull);                 // chunks 0..63 with events
  uint64_t nzc1 = __ballot(f1 != 0ull);                 // 64..127
  uint64_t nzc2 = __ballot((l < 4) && (f2 != 0ull));    // 128..131
  int cnt = ecnt[n]; if (cnt > ECAP) cnt = ECAP;
  const uint32_t* E = eb + (size_t)n * ECAP;
  uint32_t Er[16];
#pragma unroll
  for (int s = 0; s < 16; ++s) {
    int k = s * 64 + l;
    Er[s] = (k < cnt) ? E[k] : 0xFFFFFFFFu;             // sentinel never matches
  }
  // single wave: LDS ops ordered via lgkmcnt; no barriers needed
  for (int seg = 0; seg < 3; ++seg) {
    uint64_t bm = (seg == 0) ? nzc0 : (seg == 1) ? nzc1 : nzc2;
    int cb = seg * 64;
    while (bm) {
      int c = cb + __builtin_ctzll(bm); bm &= bm - 1;
      uint64_t F = Fl[c];                               // uniform broadcast read
      while (F) {
        int b = __builtin_ctzll(F); F &= F - 1;
        uint64_t cur = Rm[c];                           // fresh (in-chunk updates visible)
        if ((cur >> b) & 1ull) continue;                // row already suppressed
        uint32_t i = (uint32_t)(c * 64 + b);
        // apply row i: all lanes scan their register edges for i-matches
#pragma unroll
        for (int s = 0; s < 16; ++s) {
          uint32_t e = Er[s];
          if ((e >> 16) == i) {
            uint32_t j = e & 0xFFFFu;                   // j > i always (k_pairs)
            atomicOr((unsigned long long*)&Rm[j >> 6], 1ull << (j & 63u));
          }
        }
        if (cnt > ERCAP) {                              // emergency overflow path
          for (int k = ERCAP + l; k < cnt; k += 64) {
            uint32_t e = E[k];
            if ((e >> 16) == i) {
              uint32_t j = e & 0xFFFFu;
              atomicOr((unsigned long long*)&Rm[j >> 6], 1ull << (j & 63u));
            }
          }
        }
      }
    }
  }
  keepw[(size_t)n * NW + l] = ~Rm[l];
  keepw[(size_t)n * NW + 64 + l] = ~Rm[64 + l];
  if (l < 4) keepw[(size_t)n * NW + 128 + l] = ~Rm[128 + l];
}

// ---------------- finalize outputs
__global__ __launch_bounds__(256) void k_final(
    const float* __restrict__ s_score, const int* __restrict__ s_label,
    const float* __restrict__ s_box, const uint64_t* __restrict__ keepw,
    float* __restrict__ out)
{
  int t = blockIdx.x * 256 + threadIdx.x;
  if (t >= NIMG * PTOT) return;
  int n = t / PTOT, p = t - n * PTOT;
  uint64_t w = keepw[(size_t)n * NW + (p >> 6)];
  float k = (float)((w >> (p & 63)) & 1ull);
  float* dets = out;
  float* lab  = out + (size_t)NIMG * PTOT * 5;
  float* kp   = out + (size_t)NIMG * PTOT * 6;
  const float* bp = s_box + (size_t)t * 4;
  float* dp = dets + (size_t)t * 5;
  dp[0] = bp[0] * k; dp[1] = bp[1] * k; dp[2] = bp[2] * k; dp[3] = bp[3] * k;
  dp[4] = s_score[t] * k;
  lab[t] = (float)s_label[t];
  kp[t]  = k;
}

extern "C" void kernel_launch(void* const* d_in, const int* in_sizes, int n_in,
                              void* d_out, int out_size, void* d_ws, size_t ws_size,
                              hipStream_t stream)
{
  const float* cls0 = (const float*)d_in[0];
  const float* cls1 = (const float*)d_in[1];
  const float* cls2 = (const float*)d_in[2];
  const float* reg0 = (const float*)d_in[3];
  const float* reg1 = (const float*)d_in[4];
  const float* reg2 = (const float*)d_in[5];
  const float* obj0 = (const float*)d_in[6];
  const float* obj1 = (const float*)d_in[7];
  const float* obj2 = (const float*)d_in[8];

  char* w = (char*)d_ws;
  uint64_t* keepw = (uint64_t*)w; w += (size_t)NIMG * NW * 8;          // 4,224 B
  uint64_t* flags = (uint64_t*)w; w += (size_t)NIMG * NW * 8;          // 4,224 B
  float* score = (float*)w;       w += (size_t)NIMG * PTOT * 4;
  int*   label = (int*)w;         w += (size_t)NIMG * PTOT * 4;
  float* boxes = (float*)w;       w += (size_t)NIMG * PTOT * 16;
  float* ss = (float*)w;          w += (size_t)NIMG * PTOT * 4;
  int*   sl = (int*)w;            w += (size_t)NIMG * PTOT * 4;
  float* sb = (float*)w;          w += (size_t)NIMG * PTOT * 16;
  float* sq = (float*)w;          w += (size_t)NIMG * PTOT * 16;
  float* sa = (float*)w;          w += (size_t)NIMG * PTOT * 4;
  unsigned* gmax = (unsigned*)w;  w += 256;
  unsigned* gmin = (unsigned*)w;  w += 256;
  int* nvalid = (int*)w;          w += 256;
  int* rank = (int*)w;            w += (size_t)NIMG * PTOT * 4;
  int* lhist = (int*)w;           w += (size_t)NIMG * NCLS * 4;        // 1,280 B
  int* bstart = (int*)w;          w += (size_t)NIMG * (NCLS + 1) * 4;  // 1,296 B
  int* cursor = (int*)w;          w += (size_t)NIMG * NCLS * 4;
  int* bidx = (int*)w;            w += (size_t)NIMG * PTOT * 4;
  uint32_t* eb = (uint32_t*)w;    w += (size_t)NIMG * ECAP * 4;        // 1 MB
  int* ecnt = (int*)w;            w += 256;

  k_init<<<dim3(4), dim3(256), 0, stream>>>(gmax, gmin, flags, nvalid, lhist, ecnt);
  k_decode<<<dim3((NIMG * PTOT * 4) / 256), dim3(256), 0, stream>>>(
      cls0, cls1, cls2, reg0, reg1, reg2, obj0, obj1, obj2,
      score, label, boxes, gmax, gmin, lhist);
  k_sort<<<dim3(NIMG), dim3(256), 0, stream>>>(score, rank, lhist, bstart, cursor);
  k_scatter<<<dim3((PTOT + 255) / 256, NIMG), dim3(256), 0, stream>>>(
      score, label, boxes, gmax, rank, nvalid, ss, sl, sb, sq, sa, cursor, bidx);
  k_pairs<<<dim3(NCLS, DMAX + 1, NIMG), dim3(256), 0, stream>>>(
      sq, sa, bstart, bidx, gmax, gmin, eb, ecnt, flags);
  k_scan<<<dim3(NIMG), dim3(64), 0, stream>>>(eb, ecnt, flags, nvalid, keepw);
  k_final<<<dim3((NIMG * PTOT + 255) / 256), dim3(256), 0, stream>>>(
      ss, sl, sb, keepw, (float*)d_out);
}